// Round 8
// baseline (620.111 us; speedup 1.0000x reference)
//
#include <hip/hip_runtime.h>
#include <math.h>

#define Bq 64
#define Hq 256
#define Lq 1024
#define HLq (Hq*Lq)        // 262144
#define BHLq (Bq*Hq*Lq)    // 16777216
#define HNq (Hq*64)        // 16384

typedef __attribute__((ext_vector_type(8))) short bf16x8;
typedef __attribute__((ext_vector_type(4))) float f32x4;

__device__ __forceinline__ float sigmoidf_(float x){ return 1.f/(1.f+expf(-x)); }
__device__ __forceinline__ unsigned short f2bf(float f){
  unsigned u = __float_as_uint(f);
  u += 0x7FFF + ((u>>16)&1);
  return (unsigned short)(u>>16);
}
__device__ __forceinline__ float bf2f(unsigned short h){ return __uint_as_float(((unsigned)h)<<16); }

// ---------------- K1a: ada linear partials. Grid (32 o-tiles, 16 k-chunks), 512 blocks.
__global__ __launch_bounds__(256) void k_ada2(const int* __restrict__ tptr,
        const float* __restrict__ ada_w, float* __restrict__ Part){
  __shared__ float Es[64][68];
  __shared__ float Ws[64][68];
  const int tid = threadIdx.x;
  const int o0 = blockIdx.x * 64;
  const int kc = blockIdx.y;
  const int k0 = kc * 64;
  const float ci = -logf(10000.f) / 511.f;
  #pragma unroll
  for (int it = 0; it < 4; ++it){
    int fidx = it*256 + tid;
    int row = fidx >> 4;        // b
    int c4  = fidx & 15;
    float tb = (float)tptr[row];
    float4 v;
    float* vp = &v.x;
    #pragma unroll
    for (int q = 0; q < 4; ++q){
      int k = k0 + c4*4 + q;
      float f = expf(ci * (float)(k & 511));
      float arg = tb * f;
      float s = (k < 512) ? sinf(arg) : cosf(arg);
      vp[q] = s * sigmoidf_(s);
    }
    *(float4*)&Es[row][c4*4] = v;
  }
  #pragma unroll
  for (int it = 0; it < 4; ++it){
    int fidx = it*256 + tid;
    int row = fidx >> 4;        // o
    int c4  = fidx & 15;
    *(float4*)&Ws[row][c4*4] = *(const float4*)(ada_w + (size_t)(o0+row)*1024 + k0 + c4*4);
  }
  __syncthreads();
  float acc[4][4] = {};
  #pragma unroll
  for (int ks = 0; ks < 16; ++ks){
    int k = ks*4;
    float4 ev[4], wv[4];
    #pragma unroll
    for (int i=0;i<4;++i) ev[i] = *(const float4*)&Es[(tid>>4) + 16*i][k];
    #pragma unroll
    for (int j=0;j<4;++j) wv[j] = *(const float4*)&Ws[(tid&15) + 16*j][k];
    #pragma unroll
    for (int i=0;i<4;++i)
      #pragma unroll
      for (int j=0;j<4;++j)
        acc[i][j] += ev[i].x*wv[j].x + ev[i].y*wv[j].y + ev[i].z*wv[j].z + ev[i].w*wv[j].w;
  }
  float* pbase = Part + (size_t)kc*131072 + o0;   // Part[kc][b][o]
  #pragma unroll
  for (int i=0;i<4;++i){
    int b = (tid>>4) + 16*i;
    #pragma unroll
    for (int j=0;j<4;++j){
      int o = (tid&15) + 16*j;
      pbase[(size_t)b*2048 + o] = acc[i][j];
    }
  }
}

// ---------------- K1b: reduce 16 K-partials + bias -> scsh (B x 2048)
__global__ void k_red(const float* __restrict__ Part, const float* __restrict__ ada_b,
                      float* __restrict__ scsh){
  int idx = blockIdx.x*256 + threadIdx.x;   // float4 index, 32768 total
  float4 s = ((const float4*)ada_b)[idx & 511];
  #pragma unroll
  for (int p = 0; p < 16; ++p){
    float4 u = ((const float4*)Part)[p*32768 + idx];
    s.x += u.x; s.y += u.y; s.z += u.z; s.w += u.w;
  }
  ((float4*)scsh)[idx] = s;
}

// ---------------- K1c: convert out_w / lin1_w / lin2_w (256x256 fp32) -> bf16, L2-resident
__global__ void k_wcvt(const float* __restrict__ w0, const float* __restrict__ w1,
                       const float* __restrict__ w2, unsigned short* __restrict__ wb){
  int idx = blockIdx.x*256 + threadIdx.x;   // float4 units, 49152 total
  const float* src = (idx < 16384) ? w0 : ((idx < 32768) ? w1 : w2);
  int loc = idx & 16383;
  float4 v = ((const float4*)src)[loc];
  uint2 pk;
  pk.x = (unsigned)f2bf(v.x) | ((unsigned)f2bf(v.y)<<16);
  pk.y = (unsigned)f2bf(v.z) | ((unsigned)f2bf(v.w)<<16);
  ((uint2*)wb)[idx] = pk;
}

// ---------------- K2: AdaLayerNorm over L per (b,h) row -> Ax (fp32)
__global__ void k_adaln(const float* __restrict__ x, const float* __restrict__ scsh,
                        float* __restrict__ A){
  const int bid = blockIdx.x;        // b*H + h
  const int b = bid >> 8;
  const int tid = threadIdx.x;
  const float4* row = (const float4*)(x + (size_t)bid*1024);
  float4 v = row[tid];
  float s = v.x+v.y+v.z+v.w;
  float ss = v.x*v.x+v.y*v.y+v.z*v.z+v.w*v.w;
  #pragma unroll
  for (int off=32; off; off>>=1){ s += __shfl_xor(s,off); ss += __shfl_xor(ss,off); }
  __shared__ float rs_[4], rss_[4];
  int lane = tid & 63, w = tid >> 6;
  if (!lane){ rs_[w]=s; rss_[w]=ss; }
  __syncthreads();
  s  = rs_[0]+rs_[1]+rs_[2]+rs_[3];
  ss = rss_[0]+rss_[1]+rss_[2]+rss_[3];
  float mean = s * (1.f/1024.f);
  float var  = ss*(1.f/1024.f) - mean*mean;
  float rstd = rsqrtf(var + 1e-5f);
  float4 sc = ((const float4*)(scsh + b*2048))[tid];
  float4 sh = ((const float4*)(scsh + b*2048 + 1024))[tid];
  float4 o;
  o.x = (v.x-mean)*rstd*(1.f+sc.x) + sh.x;
  o.y = (v.y-mean)*rstd*(1.f+sc.y) + sh.y;
  o.z = (v.z-mean)*rstd*(1.f+sc.z) + sh.z;
  o.w = (v.w-mean)*rstd*(1.f+sc.w) + sh.w;
  ((float4*)(A + (size_t)bid*1024))[tid] = o;
}

// ---------------- K3: channel LayerNorm over H per (b,l) -> z in bf16
__global__ void k_chln(const float* __restrict__ A, const float* __restrict__ nw,
                       const float* __restrict__ nb, unsigned short* __restrict__ Zb){
  const int b = blockIdx.y;
  const int l = blockIdx.x*256 + threadIdx.x;
  const float* base = A + (size_t)b*HLq + l;
  float s=0.f, ss=0.f;
  for (int h=0; h<256; ++h){ float v = base[h*1024]; s+=v; ss+=v*v; }
  float mean = s*(1.f/256.f);
  float var  = ss*(1.f/256.f) - mean*mean;
  float rstd = rsqrtf(var+1e-5f);
  unsigned short* zb = Zb + (size_t)b*HLq + l;
  for (int h=0; h<256; ++h){
    float v = base[h*1024];
    zb[h*1024] = f2bf((v-mean)*rstd*nw[h] + nb[h]);
  }
}

// ---------------- K4: SSM kernels K0/K1 (2,H,L) via direct Vandermonde sum (fp32)
__global__ void k_ssmk(const float* __restrict__ log_dt, const float* __restrict__ A_re,
                       const float* __restrict__ A_im, const float* __restrict__ C_re,
                       const float* __restrict__ C_im, float* __restrict__ Kbuf){
  const int h = blockIdx.y;
  const int tid = threadIdx.x;
  __shared__ float dre[64], dim_[64], c0r[64], c0i[64], c1r[64], c1i[64];
  if (tid < 64){
    int n = tid;
    float dt = expf(log_dt[h]);
    float Ar = -expf(A_re[h*64+n]);
    float Ai = A_im[h*64+n];
    float dr = dt*Ar, di = dt*Ai;
    float er = expf(dr);
    float dAr = er*cosf(di), dAi = er*sinf(di);
    float den = Ar*Ar + Ai*Ai;
    float nr = dAr - 1.f, ni = dAi;
    float qr = (nr*Ar + ni*Ai)/den;
    float qi = (ni*Ar - nr*Ai)/den;
    float C0r = C_re[h*64+n],       C0i = C_im[h*64+n];
    float C1r = C_re[HNq + h*64+n], C1i = C_im[HNq + h*64+n];
    c0r[n] = C0r*qr - C0i*qi; c0i[n] = C0r*qi + C0i*qr;
    c1r[n] = C1r*qr - C1i*qi; c1i[n] = C1r*qi + C1i*qr;
    dre[n] = dr; dim_[n] = di;
  }
  __syncthreads();
  int l = blockIdx.x*256 + tid;
  float lf = (float)l;
  float a0=0.f, a1=0.f;
  for (int n=0;n<64;++n){
    float e  = expf(lf*dre[n]);
    float ph = lf*dim_[n];
    float wr = e*cosf(ph), wi = e*sinf(ph);
    a0 += c0r[n]*wr - c0i[n]*wi;
    a1 += c1r[n]*wr - c1i[n]*wi;
  }
  Kbuf[h*1024 + l]       = 2.f*a0;
  Kbuf[HLq + h*1024 + l] = 2.f*a1;
}

// ---------------- K5: bidirectional Toeplitz conv via bf16 MFMA + D*z + GELU -> Cb bf16
__global__ __launch_bounds__(256,2) void k_conv(const unsigned short* __restrict__ Zb,
        const float* __restrict__ Kbuf, const float* __restrict__ Dp,
        unsigned short* __restrict__ Cb){
  __shared__ unsigned short kcopy[8][2056];   // stride 2056 el = 1028 dw = 4 mod 32 (bank spread)
  __shared__ unsigned short As[64][136];      // z tile, Kc=128, +8 pad
  const int tid = threadIdx.x;
  const int h  = blockIdx.y;
  const int l0 = blockIdx.x * 512;
  const float* K0 = Kbuf + h*1024;
  const float* K1 = Kbuf + HLq + h*1024;
  for (int idx = tid; idx < 8*2056; idx += 256){
    int s = idx / 2056;
    int i = idx - s*2056;
    int q = 2046 - i - s;
    float v = 0.f;
    if (q >= 0) v = (q >= 1023) ? K0[q-1023] : K1[1022-q];
    kcopy[s][i] = f2bf(v);
  }
  const int lane = tid & 63;
  const int w    = tid >> 6;
  const int ln   = lane & 15;
  const int quad = lane >> 4;
  int kofs[8];
  #pragma unroll
  for (int nt=0; nt<8; ++nt){
    int l = l0 + w*128 + nt*16 + ln;
    int d = 1023 - l;              // krev base = d + j
    int s = d & 7;
    kofs[nt] = s*2056 + (d - s) + quad*8;   // 16B-aligned element offset
  }
  const unsigned short* kbase = &kcopy[0][0];
  f32x4 acc[4][8] = {};
  for (int c = 0; c < 8; ++c){
    __syncthreads();
    #pragma unroll
    for (int pass = 0; pass < 4; ++pass){
      int b = pass*16 + (tid>>4);
      int col = (tid & 15)*8;
      *(uint4*)&As[b][col] = *(const uint4*)(Zb + ((size_t)b*256 + h)*1024 + c*128 + col);
    }
    __syncthreads();
    #pragma unroll
    for (int ks = 0; ks < 4; ++ks){
      int kk = ks*32 + quad*8;
      bf16x8 af[4];
      #pragma unroll
      for (int mt=0; mt<4; ++mt) af[mt] = *(const bf16x8*)&As[mt*16+ln][kk];
      int jb = c*128 + ks*32;
      bf16x8 bv[8];
      #pragma unroll
      for (int nt=0; nt<8; ++nt) bv[nt] = *(const bf16x8*)(kbase + kofs[nt] + jb);
      #pragma unroll
      for (int mt=0; mt<4; ++mt)
        #pragma unroll
        for (int nt=0; nt<8; ++nt)
          acc[mt][nt] = __builtin_amdgcn_mfma_f32_16x16x32_bf16(af[mt], bv[nt], acc[mt][nt], 0,0,0);
    }
  }
  float Dh = Dp[h];
  #pragma unroll
  for (int mt=0; mt<4; ++mt){
    #pragma unroll
    for (int reg=0; reg<4; ++reg){
      int b = mt*16 + quad*4 + reg;
      const unsigned short* zrow = Zb + ((size_t)b*256+h)*1024;
      unsigned short* crow = Cb + ((size_t)b*256+h)*1024;
      #pragma unroll
      for (int nt=0; nt<8; ++nt){
        int l = l0 + w*128 + nt*16 + ln;
        float y = acc[mt][nt][reg] + Dh*bf2f(zrow[l]);
        float g = 0.5f*y*(1.f + erff(y*0.70710678118f));
        crow[l] = f2bf(g);
      }
    }
  }
}

// ---------------- K6: FUSED gate + dual output GEMM (v6).
// Geometry: 256 threads, tile 32 l x 256 o, grid (32,64); Ts[32][264] reused u->g.
// 4-phase o-half split to cut peak live VGPR to ~55-60:
//   GEMM1-h0 -> gate -> pack g in regs; GEMM1-h1 -> gate -> pack;
//   barrier; write g; barrier; GEMM2-h0 + epilogue; GEMM2-h1 + epilogue.
// launch_bounds(256,4): allocator targets the 64-VGPR tier (observed r4); demand
// now fits -> 8 waves/SIMD, 8 blocks/CU (LDS 135KB < 160). Gate: WRITE must
// stay ~131MB (no scratch); if >=180MB the tier is unreachable -> revert next round.
__global__ __launch_bounds__(256,4)
void k_fuse(const unsigned short* __restrict__ U,
        const unsigned short* __restrict__ Wob, const float* __restrict__ out_b,
        const unsigned short* __restrict__ W1b, const float* __restrict__ b1,
        const unsigned short* __restrict__ W2b, const float* __restrict__ b2,
        const float* __restrict__ Ax, float* __restrict__ out){
  __shared__ unsigned short Ts[32][264];
  const int tid = threadIdx.x;
  const int l0 = blockIdx.x * 32;
  const int b  = blockIdx.y;
  const int lane = tid & 63, w = tid >> 6, ln = lane & 15, quad = lane >> 4;
  // ---- stage: Ts[l][i] = U[b][i][l0+l]  (transpose gather, 4 i per uint2)
  {
    int l  = tid & 31;
    int g0 = tid >> 5;             // 0..7
    #pragma unroll
    for (int it = 0; it < 8; ++it){
      int i4 = it*8 + g0;          // uint2 group (4 i values), 0..63
      const unsigned short* usrc = U + ((size_t)b*256 + i4*4)*1024 + l0 + l;
      unsigned short e0 = usrc[0], e1 = usrc[1024], e2 = usrc[2048], e3 = usrc[3072];
      uint2 val; val.x = (unsigned)e0 | ((unsigned)e1<<16); val.y = (unsigned)e2 | ((unsigned)e3<<16);
      *(uint2*)&Ts[l][i4*4] = val;
    }
  }
  __syncthreads();
  // ---- GEMM1 + gate in two o-halves; g held packed in regs until barrier
  uint2 gpk[2][2][2];   // [half][mtl][nt]
  #pragma unroll
  for (int half = 0; half < 2; ++half){
    f32x4 acc1[2][2] = {};
    #pragma unroll
    for (int ks = 0; ks < 8; ++ks){
      int kk = ks*32 + quad*8;
      bf16x8 af[2], bv[2];
      #pragma unroll
      for (int mtl=0;mtl<2;++mtl)
        af[mtl] = *(const bf16x8*)(Wob + (size_t)(w*64+(half*2+mtl)*16+ln)*256 + kk);
      #pragma unroll
      for (int nt=0;nt<2;++nt) bv[nt] = *(const bf16x8*)&Ts[nt*16+ln][kk];
      #pragma unroll
      for (int mtl=0;mtl<2;++mtl)
        #pragma unroll
        for (int nt=0;nt<2;++nt)
          acc1[mtl][nt] = __builtin_amdgcn_mfma_f32_16x16x32_bf16(af[mtl], bv[nt], acc1[mtl][nt],0,0,0);
    }
    // gate: g = tanh(v)*sigmoid(v) = (1-t)/(1+t^2), t = e^-v (clamped)
    #pragma unroll
    for (int mtl=0;mtl<2;++mtl){
      #pragma unroll
      for (int reg=0;reg<4;++reg){
        int o = w*64 + (half*2+mtl)*16 + quad*4 + reg;
        float bo = out_b[o];
        const float* arow = Ax + ((size_t)b*256 + o)*1024 + l0;
        #pragma unroll
        for (int nt=0;nt<2;++nt){
          int l = nt*16 + ln;
          float v = acc1[mtl][nt][reg] + bo + arow[l];
          float t = expf(-fmaxf(v, -15.f));
          acc1[mtl][nt][reg] = (1.f - t)/(1.f + t*t);
        }
      }
    }
    #pragma unroll
    for (int mtl=0;mtl<2;++mtl)
      #pragma unroll
      for (int nt=0;nt<2;++nt){
        uint2 pk;
        pk.x = (unsigned)f2bf(acc1[mtl][nt][0]) | ((unsigned)f2bf(acc1[mtl][nt][1])<<16);
        pk.y = (unsigned)f2bf(acc1[mtl][nt][2]) | ((unsigned)f2bf(acc1[mtl][nt][3])<<16);
        gpk[half][mtl][nt] = pk;
      }
  }
  __syncthreads();            // all waves done reading u from Ts
  // ---- write g into the same tile; column dim is now o
  #pragma unroll
  for (int half=0;half<2;++half)
    #pragma unroll
    for (int mtl=0;mtl<2;++mtl){
      int ob = w*64 + (half*2+mtl)*16 + quad*4;
      #pragma unroll
      for (int nt=0;nt<2;++nt)
        *(uint2*)&Ts[nt*16+ln][ob] = gpk[half][mtl][nt];
    }
  __syncthreads();
  // ---- GEMM2 (dual), two o-halves: live accs 32 VGPR
  #pragma unroll
  for (int half = 0; half < 2; ++half){
    f32x4 accA[2][2] = {}, accB[2][2] = {};
    #pragma unroll
    for (int ks = 0; ks < 8; ++ks){
      int kk = ks*32 + quad*8;
      bf16x8 bv[2];
      #pragma unroll
      for (int nt=0;nt<2;++nt) bv[nt] = *(const bf16x8*)&Ts[nt*16+ln][kk];
      #pragma unroll
      for (int mt=0;mt<2;++mt){
        int orow = w*64 + (half*2+mt)*16 + ln;
        bf16x8 a1 = *(const bf16x8*)(W1b + (size_t)orow*256 + kk);
        #pragma unroll
        for (int nt=0;nt<2;++nt)
          accA[mt][nt] = __builtin_amdgcn_mfma_f32_16x16x32_bf16(a1, bv[nt], accA[mt][nt],0,0,0);
        bf16x8 a2 = *(const bf16x8*)(W2b + (size_t)orow*256 + kk);
        #pragma unroll
        for (int nt=0;nt<2;++nt)
          accB[mt][nt] = __builtin_amdgcn_mfma_f32_16x16x32_bf16(a2, bv[nt], accB[mt][nt],0,0,0);
      }
    }
    // epilogue for this half (Ax re-read; L2-hot)
    #pragma unroll
    for (int mt=0;mt<2;++mt){
      #pragma unroll
      for (int reg=0;reg<4;++reg){
        int o = w*64 + (half*2+mt)*16 + quad*4 + reg;
        float bo1 = b1[o], bo2 = b2[o];
        const float* arow = Ax + ((size_t)b*256 + o)*1024 + l0;
        float* o1row = out + ((size_t)b*256 + o)*1024 + l0;
        float* o2row = o1row + BHLq;
        #pragma unroll
        for (int nt=0;nt<2;++nt){
          int l = nt*16 + ln;
          o1row[l] = accA[mt][nt][reg] + bo1 + arow[l];
          o2row[l] = accB[mt][nt][reg] + bo2;
        }
      }
    }
  }
}

extern "C" void kernel_launch(void* const* d_in, const int* in_sizes, int n_in,
                              void* d_out, int out_size, void* d_ws, size_t ws_size,
                              hipStream_t stream){
  const float* x      = (const float*)d_in[0];
  const int*   t      = (const int*)  d_in[1];
  const float* ada_w  = (const float*)d_in[2];
  const float* ada_b  = (const float*)d_in[3];
  const float* norm_w = (const float*)d_in[4];
  const float* norm_b = (const float*)d_in[5];
  const float* log_dt = (const float*)d_in[6];
  const float* A_re   = (const float*)d_in[7];
  const float* A_im   = (const float*)d_in[8];
  const float* C_re   = (const float*)d_in[9];
  const float* C_im   = (const float*)d_in[10];
  const float* Dp     = (const float*)d_in[11];
  const float* out_w  = (const float*)d_in[12];
  const float* out_b  = (const float*)d_in[13];
  const float* lin1_w = (const float*)d_in[14];
  const float* lin1_b = (const float*)d_in[15];
  const float* lin2_w = (const float*)d_in[16];
  const float* lin2_b = (const float*)d_in[17];

  float* Ax            = (float*)d_ws;                     // x1 fp32, BHL
  unsigned short* Zb   = (unsigned short*)(Ax + BHLq);     // z bf16, BHL
  unsigned short* Cb   = Zb + BHLq;                        // gelu(y) bf16, BHL
  float* Kbuf          = (float*)(Cb + BHLq);              // 2*H*L fp32
  float* Part          = Kbuf + 2*HLq;                     // 16 x B x 2048 fp32 partials
  float* scsh          = Part + 16*64*2048;                // B*2048 fp32
  unsigned short* wb   = (unsigned short*)(scsh + 64*2048);// 3 x 256*256 bf16 weights
  float* out           = (float*)d_out;

  k_wcvt  <<<192, 256, 0, stream>>>(out_w, lin1_w, lin2_w, wb);
  k_ada2  <<<dim3(32, 16), 256, 0, stream>>>(t, ada_w, Part);
  k_red   <<<128, 256, 0, stream>>>(Part, ada_b, scsh);
  k_adaln <<<Bq*Hq, 256, 0, stream>>>(x, scsh, Ax);
  k_chln  <<<dim3(4, Bq), 256, 0, stream>>>(Ax, norm_w, norm_b, Zb);
  k_ssmk  <<<dim3(4, Hq), 256, 0, stream>>>(log_dt, A_re, A_im, C_re, C_im, Kbuf);
  k_conv  <<<dim3(2, Hq), 256, 0, stream>>>(Zb, Kbuf, Dp, Cb);
  k_fuse  <<<dim3(32, Bq), 256, 0, stream>>>(Cb, wb, out_b, wb + 65536, lin1_b,
                                             wb + 131072, lin2_b, Ax, out);
}

// Round 9
// 502.065 us; speedup vs baseline: 1.2351x; 1.2351x over previous
//
#include <hip/hip_runtime.h>
#include <math.h>

#define Bq 64
#define Hq 256
#define Lq 1024
#define HLq (Hq*Lq)        // 262144
#define BHLq (Bq*Hq*Lq)    // 16777216
#define HNq (Hq*64)        // 16384

typedef __attribute__((ext_vector_type(8))) short bf16x8;
typedef __attribute__((ext_vector_type(4))) float f32x4;

__device__ __forceinline__ float sigmoidf_(float x){ return 1.f/(1.f+expf(-x)); }
__device__ __forceinline__ unsigned short f2bf(float f){
  unsigned u = __float_as_uint(f);
  u += 0x7FFF + ((u>>16)&1);
  return (unsigned short)(u>>16);
}
__device__ __forceinline__ float bf2f(unsigned short h){ return __uint_as_float(((unsigned)h)<<16); }

// ---------------- K1a: ada linear partials. Grid (32 o-tiles, 16 k-chunks), 512 blocks.
__global__ __launch_bounds__(256) void k_ada2(const int* __restrict__ tptr,
        const float* __restrict__ ada_w, float* __restrict__ Part){
  __shared__ float Es[64][68];
  __shared__ float Ws[64][68];
  const int tid = threadIdx.x;
  const int o0 = blockIdx.x * 64;
  const int kc = blockIdx.y;
  const int k0 = kc * 64;
  const float ci = -logf(10000.f) / 511.f;
  #pragma unroll
  for (int it = 0; it < 4; ++it){
    int fidx = it*256 + tid;
    int row = fidx >> 4;        // b
    int c4  = fidx & 15;
    float tb = (float)tptr[row];
    float4 v;
    float* vp = &v.x;
    #pragma unroll
    for (int q = 0; q < 4; ++q){
      int k = k0 + c4*4 + q;
      float f = expf(ci * (float)(k & 511));
      float arg = tb * f;
      float s = (k < 512) ? sinf(arg) : cosf(arg);
      vp[q] = s * sigmoidf_(s);
    }
    *(float4*)&Es[row][c4*4] = v;
  }
  #pragma unroll
  for (int it = 0; it < 4; ++it){
    int fidx = it*256 + tid;
    int row = fidx >> 4;        // o
    int c4  = fidx & 15;
    *(float4*)&Ws[row][c4*4] = *(const float4*)(ada_w + (size_t)(o0+row)*1024 + k0 + c4*4);
  }
  __syncthreads();
  float acc[4][4] = {};
  #pragma unroll
  for (int ks = 0; ks < 16; ++ks){
    int k = ks*4;
    float4 ev[4], wv[4];
    #pragma unroll
    for (int i=0;i<4;++i) ev[i] = *(const float4*)&Es[(tid>>4) + 16*i][k];
    #pragma unroll
    for (int j=0;j<4;++j) wv[j] = *(const float4*)&Ws[(tid&15) + 16*j][k];
    #pragma unroll
    for (int i=0;i<4;++i)
      #pragma unroll
      for (int j=0;j<4;++j)
        acc[i][j] += ev[i].x*wv[j].x + ev[i].y*wv[j].y + ev[i].z*wv[j].z + ev[i].w*wv[j].w;
  }
  float* pbase = Part + (size_t)kc*131072 + o0;   // Part[kc][b][o]
  #pragma unroll
  for (int i=0;i<4;++i){
    int b = (tid>>4) + 16*i;
    #pragma unroll
    for (int j=0;j<4;++j){
      int o = (tid&15) + 16*j;
      pbase[(size_t)b*2048 + o] = acc[i][j];
    }
  }
}

// ---------------- K1b: reduce 16 K-partials + bias -> scsh (B x 2048)
__global__ void k_red(const float* __restrict__ Part, const float* __restrict__ ada_b,
                      float* __restrict__ scsh){
  int idx = blockIdx.x*256 + threadIdx.x;   // float4 index, 32768 total
  float4 s = ((const float4*)ada_b)[idx & 511];
  #pragma unroll
  for (int p = 0; p < 16; ++p){
    float4 u = ((const float4*)Part)[p*32768 + idx];
    s.x += u.x; s.y += u.y; s.z += u.z; s.w += u.w;
  }
  ((float4*)scsh)[idx] = s;
}

// ---------------- K1c: convert out_w / lin1_w / lin2_w (256x256 fp32) -> bf16, L2-resident
__global__ void k_wcvt(const float* __restrict__ w0, const float* __restrict__ w1,
                       const float* __restrict__ w2, unsigned short* __restrict__ wb){
  int idx = blockIdx.x*256 + threadIdx.x;   // float4 units, 49152 total
  const float* src = (idx < 16384) ? w0 : ((idx < 32768) ? w1 : w2);
  int loc = idx & 16383;
  float4 v = ((const float4*)src)[loc];
  uint2 pk;
  pk.x = (unsigned)f2bf(v.x) | ((unsigned)f2bf(v.y)<<16);
  pk.y = (unsigned)f2bf(v.z) | ((unsigned)f2bf(v.w)<<16);
  ((uint2*)wb)[idx] = pk;
}

// ---------------- K2: AdaLayerNorm over L per (b,h) row -> Ax (fp32)
__global__ void k_adaln(const float* __restrict__ x, const float* __restrict__ scsh,
                        float* __restrict__ A){
  const int bid = blockIdx.x;        // b*H + h
  const int b = bid >> 8;
  const int tid = threadIdx.x;
  const float4* row = (const float4*)(x + (size_t)bid*1024);
  float4 v = row[tid];
  float s = v.x+v.y+v.z+v.w;
  float ss = v.x*v.x+v.y*v.y+v.z*v.z+v.w*v.w;
  #pragma unroll
  for (int off=32; off; off>>=1){ s += __shfl_xor(s,off); ss += __shfl_xor(ss,off); }
  __shared__ float rs_[4], rss_[4];
  int lane = tid & 63, w = tid >> 6;
  if (!lane){ rs_[w]=s; rss_[w]=ss; }
  __syncthreads();
  s  = rs_[0]+rs_[1]+rs_[2]+rs_[3];
  ss = rss_[0]+rss_[1]+rss_[2]+rss_[3];
  float mean = s * (1.f/1024.f);
  float var  = ss*(1.f/1024.f) - mean*mean;
  float rstd = rsqrtf(var + 1e-5f);
  float4 sc = ((const float4*)(scsh + b*2048))[tid];
  float4 sh = ((const float4*)(scsh + b*2048 + 1024))[tid];
  float4 o;
  o.x = (v.x-mean)*rstd*(1.f+sc.x) + sh.x;
  o.y = (v.y-mean)*rstd*(1.f+sc.y) + sh.y;
  o.z = (v.z-mean)*rstd*(1.f+sc.z) + sh.z;
  o.w = (v.w-mean)*rstd*(1.f+sc.w) + sh.w;
  ((float4*)(A + (size_t)bid*1024))[tid] = o;
}

// ---------------- K3a: channel-LN stats: S[b][l], SS[b][l] = sum/sumsq over h.
// Grid (16, B): block = 64 l x 4 h-chunks; coalesced loads, 4x h-parallelism,
// LDS combine. Replaces pass 1 of old k_chln (256 blocks, 1/CU, latency-bound).
__global__ __launch_bounds__(256) void k_chst(const float* __restrict__ A,
        float* __restrict__ S, float* __restrict__ SS){
  const int b  = blockIdx.y;
  const int lt = threadIdx.x & 63;
  const int hc = threadIdx.x >> 6;          // 0..3
  const int l  = blockIdx.x*64 + lt;
  const float* p = A + (size_t)b*HLq + (size_t)hc*64*1024 + l;
  float s = 0.f, ss = 0.f;
  #pragma unroll 8
  for (int h = 0; h < 64; ++h){ float v = p[(size_t)h*1024]; s += v; ss += v*v; }
  __shared__ float sp[4][64], ssp[4][64];
  sp[hc][lt] = s; ssp[hc][lt] = ss;
  __syncthreads();
  if (threadIdx.x < 64){
    int li = threadIdx.x;
    float st  = sp[0][li]+sp[1][li]+sp[2][li]+sp[3][li];
    float sst = ssp[0][li]+ssp[1][li]+ssp[2][li]+ssp[3][li];
    S [b*1024 + blockIdx.x*64 + li] = st;
    SS[b*1024 + blockIdx.x*64 + li] = sst;
  }
}

// ---------------- K3b: channel-LN normalize: elementwise float4 -> ushort4 bf16.
// 16384 blocks, pure streaming. Replaces pass 2 of old k_chln.
__global__ __launch_bounds__(256) void k_chnm(const float* __restrict__ A,
        const float* __restrict__ S, const float* __restrict__ SS,
        const float* __restrict__ nw, const float* __restrict__ nb,
        unsigned short* __restrict__ Zb){
  int idx = blockIdx.x*256 + threadIdx.x;   // float4 index, BHL/4 = 4194304 total
  int b   = idx >> 16;                      // 65536 float4 per b
  int rem = idx & 65535;
  int h   = rem >> 8;
  int l4  = rem & 255;
  float4 v  = ((const float4*)(A + (size_t)b*HLq + (size_t)h*1024))[l4];
  float4 s4 = ((const float4*)(S  + b*1024))[l4];
  float4 q4 = ((const float4*)(SS + b*1024))[l4];
  float w_ = nw[h], bb = nb[h];
  float m, r;
  unsigned short ox, oy, oz, ow;
  m = s4.x*(1.f/256.f); r = rsqrtf(q4.x*(1.f/256.f) - m*m + 1e-5f); ox = f2bf((v.x-m)*r*w_ + bb);
  m = s4.y*(1.f/256.f); r = rsqrtf(q4.y*(1.f/256.f) - m*m + 1e-5f); oy = f2bf((v.y-m)*r*w_ + bb);
  m = s4.z*(1.f/256.f); r = rsqrtf(q4.z*(1.f/256.f) - m*m + 1e-5f); oz = f2bf((v.z-m)*r*w_ + bb);
  m = s4.w*(1.f/256.f); r = rsqrtf(q4.w*(1.f/256.f) - m*m + 1e-5f); ow = f2bf((v.w-m)*r*w_ + bb);
  uint2 pk;
  pk.x = (unsigned)ox | ((unsigned)oy<<16);
  pk.y = (unsigned)oz | ((unsigned)ow<<16);
  ((uint2*)Zb)[idx] = pk;
}

// ---------------- K4: SSM kernels K0/K1 (2,H,L) via direct Vandermonde sum (fp32)
__global__ void k_ssmk(const float* __restrict__ log_dt, const float* __restrict__ A_re,
                       const float* __restrict__ A_im, const float* __restrict__ C_re,
                       const float* __restrict__ C_im, float* __restrict__ Kbuf){
  const int h = blockIdx.y;
  const int tid = threadIdx.x;
  __shared__ float dre[64], dim_[64], c0r[64], c0i[64], c1r[64], c1i[64];
  if (tid < 64){
    int n = tid;
    float dt = expf(log_dt[h]);
    float Ar = -expf(A_re[h*64+n]);
    float Ai = A_im[h*64+n];
    float dr = dt*Ar, di = dt*Ai;
    float er = expf(dr);
    float dAr = er*cosf(di), dAi = er*sinf(di);
    float den = Ar*Ar + Ai*Ai;
    float nr = dAr - 1.f, ni = dAi;
    float qr = (nr*Ar + ni*Ai)/den;
    float qi = (ni*Ar - nr*Ai)/den;
    float C0r = C_re[h*64+n],       C0i = C_im[h*64+n];
    float C1r = C_re[HNq + h*64+n], C1i = C_im[HNq + h*64+n];
    c0r[n] = C0r*qr - C0i*qi; c0i[n] = C0r*qi + C0i*qr;
    c1r[n] = C1r*qr - C1i*qi; c1i[n] = C1r*qi + C1i*qr;
    dre[n] = dr; dim_[n] = di;
  }
  __syncthreads();
  int l = blockIdx.x*256 + tid;
  float lf = (float)l;
  float a0=0.f, a1=0.f;
  for (int n=0;n<64;++n){
    float e  = expf(lf*dre[n]);
    float ph = lf*dim_[n];
    float wr = e*cosf(ph), wi = e*sinf(ph);
    a0 += c0r[n]*wr - c0i[n]*wi;
    a1 += c1r[n]*wr - c1i[n]*wi;
  }
  Kbuf[h*1024 + l]       = 2.f*a0;
  Kbuf[HLq + h*1024 + l] = 2.f*a1;
}

// ---------------- K5: bidirectional Toeplitz conv via bf16 MFMA + D*z + GELU -> Cb bf16
__global__ __launch_bounds__(256,2) void k_conv(const unsigned short* __restrict__ Zb,
        const float* __restrict__ Kbuf, const float* __restrict__ Dp,
        unsigned short* __restrict__ Cb){
  __shared__ unsigned short kcopy[8][2056];   // stride 2056 el = 1028 dw = 4 mod 32 (bank spread)
  __shared__ unsigned short As[64][136];      // z tile, Kc=128, +8 pad
  const int tid = threadIdx.x;
  const int h  = blockIdx.y;
  const int l0 = blockIdx.x * 512;
  const float* K0 = Kbuf + h*1024;
  const float* K1 = Kbuf + HLq + h*1024;
  for (int idx = tid; idx < 8*2056; idx += 256){
    int s = idx / 2056;
    int i = idx - s*2056;
    int q = 2046 - i - s;
    float v = 0.f;
    if (q >= 0) v = (q >= 1023) ? K0[q-1023] : K1[1022-q];
    kcopy[s][i] = f2bf(v);
  }
  const int lane = tid & 63;
  const int w    = tid >> 6;
  const int ln   = lane & 15;
  const int quad = lane >> 4;
  int kofs[8];
  #pragma unroll
  for (int nt=0; nt<8; ++nt){
    int l = l0 + w*128 + nt*16 + ln;
    int d = 1023 - l;              // krev base = d + j
    int s = d & 7;
    kofs[nt] = s*2056 + (d - s) + quad*8;   // 16B-aligned element offset
  }
  const unsigned short* kbase = &kcopy[0][0];
  f32x4 acc[4][8] = {};
  for (int c = 0; c < 8; ++c){
    __syncthreads();
    #pragma unroll
    for (int pass = 0; pass < 4; ++pass){
      int b = pass*16 + (tid>>4);
      int col = (tid & 15)*8;
      *(uint4*)&As[b][col] = *(const uint4*)(Zb + ((size_t)b*256 + h)*1024 + c*128 + col);
    }
    __syncthreads();
    #pragma unroll
    for (int ks = 0; ks < 4; ++ks){
      int kk = ks*32 + quad*8;
      bf16x8 af[4];
      #pragma unroll
      for (int mt=0; mt<4; ++mt) af[mt] = *(const bf16x8*)&As[mt*16+ln][kk];
      int jb = c*128 + ks*32;
      bf16x8 bv[8];
      #pragma unroll
      for (int nt=0; nt<8; ++nt) bv[nt] = *(const bf16x8*)(kbase + kofs[nt] + jb);
      #pragma unroll
      for (int mt=0; mt<4; ++mt)
        #pragma unroll
        for (int nt=0; nt<8; ++nt)
          acc[mt][nt] = __builtin_amdgcn_mfma_f32_16x16x32_bf16(af[mt], bv[nt], acc[mt][nt], 0,0,0);
    }
  }
  float Dh = Dp[h];
  #pragma unroll
  for (int mt=0; mt<4; ++mt){
    #pragma unroll
    for (int reg=0; reg<4; ++reg){
      int b = mt*16 + quad*4 + reg;
      const unsigned short* zrow = Zb + ((size_t)b*256+h)*1024;
      unsigned short* crow = Cb + ((size_t)b*256+h)*1024;
      #pragma unroll
      for (int nt=0; nt<8; ++nt){
        int l = l0 + w*128 + nt*16 + ln;
        float y = acc[mt][nt][reg] + Dh*bf2f(zrow[l]);
        float g = 0.5f*y*(1.f + erff(y*0.70710678118f));
        crow[l] = f2bf(g);
      }
    }
  }
}

// ---------------- K6: FUSED gate + dual output GEMM (v5 revert — measured 139us, VGPR 88, no spill).
__global__ __launch_bounds__(256,2)
void k_fuse(const unsigned short* __restrict__ U,
        const unsigned short* __restrict__ Wob, const float* __restrict__ out_b,
        const unsigned short* __restrict__ W1b, const float* __restrict__ b1,
        const unsigned short* __restrict__ W2b, const float* __restrict__ b2,
        const float* __restrict__ Ax, float* __restrict__ out){
  __shared__ unsigned short Ts[32][264];
  const int tid = threadIdx.x;
  const int l0 = blockIdx.x * 32;
  const int b  = blockIdx.y;
  const int lane = tid & 63, w = tid >> 6, ln = lane & 15, quad = lane >> 4;
  // ---- stage: Ts[l][i] = U[b][i][l0+l]  (transpose gather, 4 i per uint2)
  {
    int l  = tid & 31;
    int g0 = tid >> 5;             // 0..7
    #pragma unroll
    for (int it = 0; it < 8; ++it){
      int i4 = it*8 + g0;          // uint2 group (4 i values), 0..63
      const unsigned short* usrc = U + ((size_t)b*256 + i4*4)*1024 + l0 + l;
      unsigned short e0 = usrc[0], e1 = usrc[1024], e2 = usrc[2048], e3 = usrc[3072];
      uint2 val; val.x = (unsigned)e0 | ((unsigned)e1<<16); val.y = (unsigned)e2 | ((unsigned)e3<<16);
      *(uint2*)&Ts[l][i4*4] = val;
    }
  }
  __syncthreads();
  // ---- GEMM1: x2 for o in [w*64, w*64+64), l-tile 32 (nt=0,1)
  f32x4 acc1[4][2] = {};
  #pragma unroll
  for (int ks = 0; ks < 8; ++ks){
    int kk = ks*32 + quad*8;
    bf16x8 af[4], bv[2];
    #pragma unroll
    for (int mt=0;mt<4;++mt) af[mt] = *(const bf16x8*)(Wob + (size_t)(w*64+mt*16+ln)*256 + kk);
    #pragma unroll
    for (int nt=0;nt<2;++nt) bv[nt] = *(const bf16x8*)&Ts[nt*16+ln][kk];
    #pragma unroll
    for (int mt=0;mt<4;++mt)
      #pragma unroll
      for (int nt=0;nt<2;++nt)
        acc1[mt][nt] = __builtin_amdgcn_mfma_f32_16x16x32_bf16(af[mt], bv[nt], acc1[mt][nt],0,0,0);
  }
  // ---- gate: g = tanh(v)*sigmoid(v) = (1-t)/(1+t^2), t = e^-v (clamped)
  #pragma unroll
  for (int mt=0;mt<4;++mt){
    #pragma unroll
    for (int reg=0;reg<4;++reg){
      int o = w*64 + mt*16 + quad*4 + reg;
      float bo = out_b[o];
      const float* arow = Ax + ((size_t)b*256 + o)*1024 + l0;
      #pragma unroll
      for (int nt=0;nt<2;++nt){
        int l = nt*16 + ln;
        float v = acc1[mt][nt][reg] + bo + arow[l];
        float t = expf(-fmaxf(v, -15.f));
        acc1[mt][nt][reg] = (1.f - t)/(1.f + t*t);
      }
    }
  }
  __syncthreads();            // all waves done reading u from Ts
  // ---- write g into the same tile; column dim is now o
  #pragma unroll
  for (int mt=0;mt<4;++mt){
    int ob = w*64 + mt*16 + quad*4;
    #pragma unroll
    for (int nt=0;nt<2;++nt){
      int l = nt*16 + ln;
      uint2 pk;
      pk.x = (unsigned)f2bf(acc1[mt][nt][0]) | ((unsigned)f2bf(acc1[mt][nt][1])<<16);
      pk.y = (unsigned)f2bf(acc1[mt][nt][2]) | ((unsigned)f2bf(acc1[mt][nt][3])<<16);
      *(uint2*)&Ts[l][ob] = pk;
    }
  }
  __syncthreads();
  // ---- GEMM2 (dual), two o-halves: live accs 32 VGPR instead of 64
  #pragma unroll
  for (int half = 0; half < 2; ++half){
    f32x4 accA[2][2] = {}, accB[2][2] = {};
    #pragma unroll
    for (int ks = 0; ks < 8; ++ks){
      int kk = ks*32 + quad*8;
      bf16x8 bv[2];
      #pragma unroll
      for (int nt=0;nt<2;++nt) bv[nt] = *(const bf16x8*)&Ts[nt*16+ln][kk];
      #pragma unroll
      for (int mt=0;mt<2;++mt){
        int orow = w*64 + (half*2+mt)*16 + ln;
        bf16x8 a1 = *(const bf16x8*)(W1b + (size_t)orow*256 + kk);
        #pragma unroll
        for (int nt=0;nt<2;++nt)
          accA[mt][nt] = __builtin_amdgcn_mfma_f32_16x16x32_bf16(a1, bv[nt], accA[mt][nt],0,0,0);
        bf16x8 a2 = *(const bf16x8*)(W2b + (size_t)orow*256 + kk);
        #pragma unroll
        for (int nt=0;nt<2;++nt)
          accB[mt][nt] = __builtin_amdgcn_mfma_f32_16x16x32_bf16(a2, bv[nt], accB[mt][nt],0,0,0);
      }
    }
    // epilogue for this half (Ax re-read; L2-hot)
    #pragma unroll
    for (int mt=0;mt<2;++mt){
      #pragma unroll
      for (int reg=0;reg<4;++reg){
        int o = w*64 + (half*2+mt)*16 + quad*4 + reg;
        float bo1 = b1[o], bo2 = b2[o];
        const float* arow = Ax + ((size_t)b*256 + o)*1024 + l0;
        float* o1row = out + ((size_t)b*256 + o)*1024 + l0;
        float* o2row = o1row + BHLq;
        #pragma unroll
        for (int nt=0;nt<2;++nt){
          int l = nt*16 + ln;
          o1row[l] = accA[mt][nt][reg] + bo1 + arow[l];
          o2row[l] = accB[mt][nt][reg] + bo2;
        }
      }
    }
  }
}

extern "C" void kernel_launch(void* const* d_in, const int* in_sizes, int n_in,
                              void* d_out, int out_size, void* d_ws, size_t ws_size,
                              hipStream_t stream){
  const float* x      = (const float*)d_in[0];
  const int*   t      = (const int*)  d_in[1];
  const float* ada_w  = (const float*)d_in[2];
  const float* ada_b  = (const float*)d_in[3];
  const float* norm_w = (const float*)d_in[4];
  const float* norm_b = (const float*)d_in[5];
  const float* log_dt = (const float*)d_in[6];
  const float* A_re   = (const float*)d_in[7];
  const float* A_im   = (const float*)d_in[8];
  const float* C_re   = (const float*)d_in[9];
  const float* C_im   = (const float*)d_in[10];
  const float* Dp     = (const float*)d_in[11];
  const float* out_w  = (const float*)d_in[12];
  const float* out_b  = (const float*)d_in[13];
  const float* lin1_w = (const float*)d_in[14];
  const float* lin1_b = (const float*)d_in[15];
  const float* lin2_w = (const float*)d_in[16];
  const float* lin2_b = (const float*)d_in[17];

  float* Ax            = (float*)d_ws;                     // x1 fp32, BHL
  unsigned short* Zb   = (unsigned short*)(Ax + BHLq);     // z bf16, BHL
  unsigned short* Cb   = Zb + BHLq;                        // gelu(y) bf16, BHL
  float* Kbuf          = (float*)(Cb + BHLq);              // 2*H*L fp32
  float* Part          = Kbuf + 2*HLq;                     // 16 x B x 2048 fp32 partials
  float* scsh          = Part + 16*64*2048;                // B*2048 fp32
  unsigned short* wb   = (unsigned short*)(scsh + 64*2048);// 3 x 256*256 bf16 weights
  float* Sst           = Part;                             // chln stats alias (Part dead after k_red)
  float* SSst          = Part + 65536;
  float* out           = (float*)d_out;

  k_wcvt  <<<192, 256, 0, stream>>>(out_w, lin1_w, lin2_w, wb);
  k_ada2  <<<dim3(32, 16), 256, 0, stream>>>(t, ada_w, Part);
  k_red   <<<128, 256, 0, stream>>>(Part, ada_b, scsh);
  k_adaln <<<Bq*Hq, 256, 0, stream>>>(x, scsh, Ax);
  k_chst  <<<dim3(16, Bq), 256, 0, stream>>>(Ax, Sst, SSst);
  k_chnm  <<<16384, 256, 0, stream>>>(Ax, Sst, SSst, norm_w, norm_b, Zb);
  k_ssmk  <<<dim3(4, Hq), 256, 0, stream>>>(log_dt, A_re, A_im, C_re, C_im, Kbuf);
  k_conv  <<<dim3(2, Hq), 256, 0, stream>>>(Zb, Kbuf, Dp, Cb);
  k_fuse  <<<dim3(32, Bq), 256, 0, stream>>>(Cb, wb, out_b, wb + 65536, lin1_b,
                                             wb + 131072, lin2_b, Ax, out);
}

// Round 10
// 453.197 us; speedup vs baseline: 1.3683x; 1.1078x over previous
//
#include <hip/hip_runtime.h>
#include <math.h>

#define Bq 64
#define Hq 256
#define Lq 1024
#define HLq (Hq*Lq)        // 262144
#define BHLq (Bq*Hq*Lq)    // 16777216
#define HNq (Hq*64)        // 16384

typedef __attribute__((ext_vector_type(8))) short bf16x8;
typedef __attribute__((ext_vector_type(4))) float f32x4;

__device__ __forceinline__ float sigmoidf_(float x){ return 1.f/(1.f+expf(-x)); }
__device__ __forceinline__ unsigned short f2bf(float f){
  unsigned u = __float_as_uint(f);
  u += 0x7FFF + ((u>>16)&1);
  return (unsigned short)(u>>16);
}
__device__ __forceinline__ float bf2f(unsigned short h){ return __uint_as_float(((unsigned)h)<<16); }

// ---------------- K1a: ada linear partials. Grid (32 o-tiles, 16 k-chunks), 512 blocks.
__global__ __launch_bounds__(256) void k_ada2(const int* __restrict__ tptr,
        const float* __restrict__ ada_w, float* __restrict__ Part){
  __shared__ float Es[64][68];
  __shared__ float Ws[64][68];
  const int tid = threadIdx.x;
  const int o0 = blockIdx.x * 64;
  const int kc = blockIdx.y;
  const int k0 = kc * 64;
  const float ci = -logf(10000.f) / 511.f;
  #pragma unroll
  for (int it = 0; it < 4; ++it){
    int fidx = it*256 + tid;
    int row = fidx >> 4;        // b
    int c4  = fidx & 15;
    float tb = (float)tptr[row];
    float4 v;
    float* vp = &v.x;
    #pragma unroll
    for (int q = 0; q < 4; ++q){
      int k = k0 + c4*4 + q;
      float f = expf(ci * (float)(k & 511));
      float arg = tb * f;
      float s = (k < 512) ? sinf(arg) : cosf(arg);
      vp[q] = s * sigmoidf_(s);
    }
    *(float4*)&Es[row][c4*4] = v;
  }
  #pragma unroll
  for (int it = 0; it < 4; ++it){
    int fidx = it*256 + tid;
    int row = fidx >> 4;        // o
    int c4  = fidx & 15;
    *(float4*)&Ws[row][c4*4] = *(const float4*)(ada_w + (size_t)(o0+row)*1024 + k0 + c4*4);
  }
  __syncthreads();
  float acc[4][4] = {};
  #pragma unroll
  for (int ks = 0; ks < 16; ++ks){
    int k = ks*4;
    float4 ev[4], wv[4];
    #pragma unroll
    for (int i=0;i<4;++i) ev[i] = *(const float4*)&Es[(tid>>4) + 16*i][k];
    #pragma unroll
    for (int j=0;j<4;++j) wv[j] = *(const float4*)&Ws[(tid&15) + 16*j][k];
    #pragma unroll
    for (int i=0;i<4;++i)
      #pragma unroll
      for (int j=0;j<4;++j)
        acc[i][j] += ev[i].x*wv[j].x + ev[i].y*wv[j].y + ev[i].z*wv[j].z + ev[i].w*wv[j].w;
  }
  float* pbase = Part + (size_t)kc*131072 + o0;   // Part[kc][b][o]
  #pragma unroll
  for (int i=0;i<4;++i){
    int b = (tid>>4) + 16*i;
    #pragma unroll
    for (int j=0;j<4;++j){
      int o = (tid&15) + 16*j;
      pbase[(size_t)b*2048 + o] = acc[i][j];
    }
  }
}

// ---------------- K1b: reduce 16 K-partials + bias -> scsh (B x 2048)
__global__ void k_red(const float* __restrict__ Part, const float* __restrict__ ada_b,
                      float* __restrict__ scsh){
  int idx = blockIdx.x*256 + threadIdx.x;   // float4 index, 32768 total
  float4 s = ((const float4*)ada_b)[idx & 511];
  #pragma unroll
  for (int p = 0; p < 16; ++p){
    float4 u = ((const float4*)Part)[p*32768 + idx];
    s.x += u.x; s.y += u.y; s.z += u.z; s.w += u.w;
  }
  ((float4*)scsh)[idx] = s;
}

// ---------------- K1c: convert out_w / lin1_w / lin2_w (256x256 fp32) -> bf16, L2-resident
__global__ void k_wcvt(const float* __restrict__ w0, const float* __restrict__ w1,
                       const float* __restrict__ w2, unsigned short* __restrict__ wb){
  int idx = blockIdx.x*256 + threadIdx.x;   // float4 units, 49152 total
  const float* src = (idx < 16384) ? w0 : ((idx < 32768) ? w1 : w2);
  int loc = idx & 16383;
  float4 v = ((const float4*)src)[loc];
  uint2 pk;
  pk.x = (unsigned)f2bf(v.x) | ((unsigned)f2bf(v.y)<<16);
  pk.y = (unsigned)f2bf(v.z) | ((unsigned)f2bf(v.w)<<16);
  ((uint2*)wb)[idx] = pk;
}

// ---------------- K2: AdaLayerNorm over L per (b,h) row -> Ax (fp32)
__global__ void k_adaln(const float* __restrict__ x, const float* __restrict__ scsh,
                        float* __restrict__ A){
  const int bid = blockIdx.x;        // b*H + h
  const int b = bid >> 8;
  const int tid = threadIdx.x;
  const float4* row = (const float4*)(x + (size_t)bid*1024);
  float4 v = row[tid];
  float s = v.x+v.y+v.z+v.w;
  float ss = v.x*v.x+v.y*v.y+v.z*v.z+v.w*v.w;
  #pragma unroll
  for (int off=32; off; off>>=1){ s += __shfl_xor(s,off); ss += __shfl_xor(ss,off); }
  __shared__ float rs_[4], rss_[4];
  int lane = tid & 63, w = tid >> 6;
  if (!lane){ rs_[w]=s; rss_[w]=ss; }
  __syncthreads();
  s  = rs_[0]+rs_[1]+rs_[2]+rs_[3];
  ss = rss_[0]+rss_[1]+rss_[2]+rss_[3];
  float mean = s * (1.f/1024.f);
  float var  = ss*(1.f/1024.f) - mean*mean;
  float rstd = rsqrtf(var + 1e-5f);
  float4 sc = ((const float4*)(scsh + b*2048))[tid];
  float4 sh = ((const float4*)(scsh + b*2048 + 1024))[tid];
  float4 o;
  o.x = (v.x-mean)*rstd*(1.f+sc.x) + sh.x;
  o.y = (v.y-mean)*rstd*(1.f+sc.y) + sh.y;
  o.z = (v.z-mean)*rstd*(1.f+sc.z) + sh.z;
  o.w = (v.w-mean)*rstd*(1.f+sc.w) + sh.w;
  ((float4*)(A + (size_t)bid*1024))[tid] = o;
}

// ---------------- K3: channel-LN, FUSED stats + normalize.
// Block = (b, 64-l chunk), 256 thr as (lt 0..63, hc 0..3). Pass 1: stats over h
// (HBM read, coalesced 256B/wave). Pass 2: re-read same 65KB (L2-hot) + write Zb.
// Removes the 67MB second HBM pass and the S/SS round-trip of the split version.
__global__ __launch_bounds__(256) void k_chln2(const float* __restrict__ A,
        const float* __restrict__ nw, const float* __restrict__ nb,
        unsigned short* __restrict__ Zb){
  const int b  = blockIdx.y;
  const int lt = threadIdx.x & 63;
  const int hc = threadIdx.x >> 6;          // 0..3
  const int l  = blockIdx.x*64 + lt;
  const float* p = A + (size_t)b*HLq + (size_t)hc*64*1024 + l;
  float s = 0.f, ss = 0.f;
  #pragma unroll 8
  for (int h = 0; h < 64; ++h){ float v = p[(size_t)h*1024]; s += v; ss += v*v; }
  __shared__ float sp[4][64], ssp[4][64];
  __shared__ float mS[64], rS[64];
  sp[hc][lt] = s; ssp[hc][lt] = ss;
  __syncthreads();
  if (threadIdx.x < 64){
    int li = threadIdx.x;
    float st  = sp[0][li]+sp[1][li]+sp[2][li]+sp[3][li];
    float sst = ssp[0][li]+ssp[1][li]+ssp[2][li]+ssp[3][li];
    float m = st*(1.f/256.f);
    float var = sst*(1.f/256.f) - m*m;
    mS[li] = m; rS[li] = rsqrtf(var + 1e-5f);
  }
  __syncthreads();
  float m = mS[lt], r = rS[lt];
  unsigned short* zb = Zb + (size_t)b*HLq + l;
  #pragma unroll 4
  for (int h = 0; h < 64; ++h){
    int hh = hc*64 + h;
    float v = p[(size_t)h*1024];
    zb[(size_t)hh*1024] = f2bf((v-m)*r*nw[hh] + nb[hh]);
  }
}

// ---------------- K4: SSM kernels K0/K1 (2,H,L) via direct Vandermonde sum (fp32)
__global__ void k_ssmk(const float* __restrict__ log_dt, const float* __restrict__ A_re,
                       const float* __restrict__ A_im, const float* __restrict__ C_re,
                       const float* __restrict__ C_im, float* __restrict__ Kbuf){
  const int h = blockIdx.y;
  const int tid = threadIdx.x;
  __shared__ float dre[64], dim_[64], c0r[64], c0i[64], c1r[64], c1i[64];
  if (tid < 64){
    int n = tid;
    float dt = expf(log_dt[h]);
    float Ar = -expf(A_re[h*64+n]);
    float Ai = A_im[h*64+n];
    float dr = dt*Ar, di = dt*Ai;
    float er = expf(dr);
    float dAr = er*cosf(di), dAi = er*sinf(di);
    float den = Ar*Ar + Ai*Ai;
    float nr = dAr - 1.f, ni = dAi;
    float qr = (nr*Ar + ni*Ai)/den;
    float qi = (ni*Ar - nr*Ai)/den;
    float C0r = C_re[h*64+n],       C0i = C_im[h*64+n];
    float C1r = C_re[HNq + h*64+n], C1i = C_im[HNq + h*64+n];
    c0r[n] = C0r*qr - C0i*qi; c0i[n] = C0r*qi + C0i*qr;
    c1r[n] = C1r*qr - C1i*qi; c1i[n] = C1r*qi + C1i*qr;
    dre[n] = dr; dim_[n] = di;
  }
  __syncthreads();
  int l = blockIdx.x*256 + tid;
  float lf = (float)l;
  float a0=0.f, a1=0.f;
  for (int n=0;n<64;++n){
    float e  = expf(lf*dre[n]);
    float ph = lf*dim_[n];
    float wr = e*cosf(ph), wi = e*sinf(ph);
    a0 += c0r[n]*wr - c0i[n]*wi;
    a1 += c1r[n]*wr - c1i[n]*wi;
  }
  Kbuf[h*1024 + l]       = 2.f*a0;
  Kbuf[HLq + h*1024 + l] = 2.f*a1;
}

// ---------------- K5: bidirectional Toeplitz conv via bf16 MFMA + D*z + GELU -> Cb bf16
__global__ __launch_bounds__(256,2) void k_conv(const unsigned short* __restrict__ Zb,
        const float* __restrict__ Kbuf, const float* __restrict__ Dp,
        unsigned short* __restrict__ Cb){
  __shared__ unsigned short kcopy[8][2056];   // stride 2056 el = 1028 dw = 4 mod 32 (bank spread)
  __shared__ unsigned short As[64][136];      // z tile, Kc=128, +8 pad
  const int tid = threadIdx.x;
  const int h  = blockIdx.y;
  const int l0 = blockIdx.x * 512;
  const float* K0 = Kbuf + h*1024;
  const float* K1 = Kbuf + HLq + h*1024;
  for (int idx = tid; idx < 8*2056; idx += 256){
    int s = idx / 2056;
    int i = idx - s*2056;
    int q = 2046 - i - s;
    float v = 0.f;
    if (q >= 0) v = (q >= 1023) ? K0[q-1023] : K1[1022-q];
    kcopy[s][i] = f2bf(v);
  }
  const int lane = tid & 63;
  const int w    = tid >> 6;
  const int ln   = lane & 15;
  const int quad = lane >> 4;
  int kofs[8];
  #pragma unroll
  for (int nt=0; nt<8; ++nt){
    int l = l0 + w*128 + nt*16 + ln;
    int d = 1023 - l;              // krev base = d + j
    int s = d & 7;
    kofs[nt] = s*2056 + (d - s) + quad*8;   // 16B-aligned element offset
  }
  const unsigned short* kbase = &kcopy[0][0];
  f32x4 acc[4][8] = {};
  for (int c = 0; c < 8; ++c){
    __syncthreads();
    #pragma unroll
    for (int pass = 0; pass < 4; ++pass){
      int b = pass*16 + (tid>>4);
      int col = (tid & 15)*8;
      *(uint4*)&As[b][col] = *(const uint4*)(Zb + ((size_t)b*256 + h)*1024 + c*128 + col);
    }
    __syncthreads();
    #pragma unroll
    for (int ks = 0; ks < 4; ++ks){
      int kk = ks*32 + quad*8;
      bf16x8 af[4];
      #pragma unroll
      for (int mt=0; mt<4; ++mt) af[mt] = *(const bf16x8*)&As[mt*16+ln][kk];
      int jb = c*128 + ks*32;
      bf16x8 bv[8];
      #pragma unroll
      for (int nt=0; nt<8; ++nt) bv[nt] = *(const bf16x8*)(kbase + kofs[nt] + jb);
      #pragma unroll
      for (int mt=0; mt<4; ++mt)
        #pragma unroll
        for (int nt=0; nt<8; ++nt)
          acc[mt][nt] = __builtin_amdgcn_mfma_f32_16x16x32_bf16(af[mt], bv[nt], acc[mt][nt], 0,0,0);
    }
  }
  float Dh = Dp[h];
  #pragma unroll
  for (int mt=0; mt<4; ++mt){
    #pragma unroll
    for (int reg=0; reg<4; ++reg){
      int b = mt*16 + quad*4 + reg;
      const unsigned short* zrow = Zb + ((size_t)b*256+h)*1024;
      unsigned short* crow = Cb + ((size_t)b*256+h)*1024;
      #pragma unroll
      for (int nt=0; nt<8; ++nt){
        int l = l0 + w*128 + nt*16 + ln;
        float y = acc[mt][nt][reg] + Dh*bf2f(zrow[l]);
        float g = 0.5f*y*(1.f + erff(y*0.70710678118f));
        crow[l] = f2bf(g);
      }
    }
  }
}

// ---------------- K6: FUSED gate + dual output GEMM (v7).
// v1 geometry (512 thr, 8 waves, 64-l tile, grid (16,64)) + single reused
// Ts[64][264] (33.8KB) + GEMM2 split into two o-halves (live accs 32).
// launch_bounds(512,3): allocator aims ~6 waves/EU = 85 VGPR; demand ~72-80
// fits -> no spill, 3 blocks/CU (LDS 101KB). If allocator gives ~95 instead we
// fall back to v1's 2 blocks/CU (~125us) — bounded downside vs current 140.
__global__ __launch_bounds__(512,3)
void k_fuse(const unsigned short* __restrict__ U,
        const unsigned short* __restrict__ Wob, const float* __restrict__ out_b,
        const unsigned short* __restrict__ W1b, const float* __restrict__ b1,
        const unsigned short* __restrict__ W2b, const float* __restrict__ b2,
        const float* __restrict__ Ax, float* __restrict__ out){
  __shared__ unsigned short Ts[64][264];
  const int tid = threadIdx.x;
  const int l0 = blockIdx.x * 64;
  const int b  = blockIdx.y;
  const int lane = tid & 63, w = tid >> 6, ln = lane & 15, quad = lane >> 4;
  // ---- stage: Ts[l][i] = U[b][i][l0+l]  (transpose gather, 4 i per uint2)
  {
    int l   = tid & 63;
    int grp = tid >> 6;            // 0..7
    #pragma unroll
    for (int it = 0; it < 8; ++it){
      int i4 = it*8 + grp;         // 0..63
      const unsigned short* usrc = U + ((size_t)b*256 + i4*4)*1024 + l0 + l;
      unsigned short e0 = usrc[0], e1 = usrc[1024], e2 = usrc[2048], e3 = usrc[3072];
      uint2 val; val.x = (unsigned)e0 | ((unsigned)e1<<16); val.y = (unsigned)e2 | ((unsigned)e3<<16);
      *(uint2*)&Ts[l][i4*4] = val;
    }
  }
  __syncthreads();
  // ---- GEMM1: x2 for o in [w*32, w*32+32), l-tile 64 (nt=0..3)
  f32x4 acc1[2][4] = {};
  #pragma unroll
  for (int ks = 0; ks < 8; ++ks){
    int kk = ks*32 + quad*8;
    bf16x8 af[2], bv[4];
    #pragma unroll
    for (int mt=0;mt<2;++mt) af[mt] = *(const bf16x8*)(Wob + (size_t)(w*32+mt*16+ln)*256 + kk);
    #pragma unroll
    for (int nt=0;nt<4;++nt) bv[nt] = *(const bf16x8*)&Ts[nt*16+ln][kk];
    #pragma unroll
    for (int mt=0;mt<2;++mt)
      #pragma unroll
      for (int nt=0;nt<4;++nt)
        acc1[mt][nt] = __builtin_amdgcn_mfma_f32_16x16x32_bf16(af[mt], bv[nt], acc1[mt][nt],0,0,0);
  }
  // ---- gate: g = tanh(v)*sigmoid(v) = (1-t)/(1+t^2), t = e^-v (clamped)
  #pragma unroll
  for (int mt=0;mt<2;++mt){
    #pragma unroll
    for (int reg=0;reg<4;++reg){
      int o = w*32 + mt*16 + quad*4 + reg;
      float bo = out_b[o];
      const float* arow = Ax + ((size_t)b*256 + o)*1024 + l0;
      #pragma unroll
      for (int nt=0;nt<4;++nt){
        int l = nt*16 + ln;
        float v = acc1[mt][nt][reg] + bo + arow[l];
        float t = expf(-fmaxf(v, -15.f));
        acc1[mt][nt][reg] = (1.f - t)/(1.f + t*t);
      }
    }
  }
  __syncthreads();            // all waves done reading u from Ts
  // ---- write g into the same tile; column dim is now o
  #pragma unroll
  for (int mt=0;mt<2;++mt){
    int ob = w*32 + mt*16 + quad*4;
    #pragma unroll
    for (int nt=0;nt<4;++nt){
      int l = nt*16 + ln;
      uint2 pk;
      pk.x = (unsigned)f2bf(acc1[mt][nt][0]) | ((unsigned)f2bf(acc1[mt][nt][1])<<16);
      pk.y = (unsigned)f2bf(acc1[mt][nt][2]) | ((unsigned)f2bf(acc1[mt][nt][3])<<16);
      *(uint2*)&Ts[l][ob] = pk;
    }
  }
  __syncthreads();
  // ---- GEMM2 (dual), two o-halves: live accs 32 VGPR
  #pragma unroll
  for (int half = 0; half < 2; ++half){
    f32x4 accA[4] = {}, accB[4] = {};
    #pragma unroll
    for (int ks = 0; ks < 8; ++ks){
      int kk = ks*32 + quad*8;
      bf16x8 bv[4];
      #pragma unroll
      for (int nt=0;nt<4;++nt) bv[nt] = *(const bf16x8*)&Ts[nt*16+ln][kk];
      int orow = w*32 + half*16 + ln;
      bf16x8 a1 = *(const bf16x8*)(W1b + (size_t)orow*256 + kk);
      #pragma unroll
      for (int nt=0;nt<4;++nt)
        accA[nt] = __builtin_amdgcn_mfma_f32_16x16x32_bf16(a1, bv[nt], accA[nt],0,0,0);
      bf16x8 a2 = *(const bf16x8*)(W2b + (size_t)orow*256 + kk);
      #pragma unroll
      for (int nt=0;nt<4;++nt)
        accB[nt] = __builtin_amdgcn_mfma_f32_16x16x32_bf16(a2, bv[nt], accB[nt],0,0,0);
    }
    // epilogue for this half (Ax re-read; L2-hot)
    #pragma unroll
    for (int reg=0;reg<4;++reg){
      int o = w*32 + half*16 + quad*4 + reg;
      float bo1 = b1[o], bo2 = b2[o];
      const float* arow = Ax + ((size_t)b*256 + o)*1024 + l0;
      float* o1row = out + ((size_t)b*256 + o)*1024 + l0;
      float* o2row = o1row + BHLq;
      #pragma unroll
      for (int nt=0;nt<4;++nt){
        int l = nt*16 + ln;
        o1row[l] = accA[nt][reg] + bo1 + arow[l];
        o2row[l] = accB[nt][reg] + bo2;
      }
    }
  }
}

extern "C" void kernel_launch(void* const* d_in, const int* in_sizes, int n_in,
                              void* d_out, int out_size, void* d_ws, size_t ws_size,
                              hipStream_t stream){
  const float* x      = (const float*)d_in[0];
  const int*   t      = (const int*)  d_in[1];
  const float* ada_w  = (const float*)d_in[2];
  const float* ada_b  = (const float*)d_in[3];
  const float* norm_w = (const float*)d_in[4];
  const float* norm_b = (const float*)d_in[5];
  const float* log_dt = (const float*)d_in[6];
  const float* A_re   = (const float*)d_in[7];
  const float* A_im   = (const float*)d_in[8];
  const float* C_re   = (const float*)d_in[9];
  const float* C_im   = (const float*)d_in[10];
  const float* Dp     = (const float*)d_in[11];
  const float* out_w  = (const float*)d_in[12];
  const float* out_b  = (const float*)d_in[13];
  const float* lin1_w = (const float*)d_in[14];
  const float* lin1_b = (const float*)d_in[15];
  const float* lin2_w = (const float*)d_in[16];
  const float* lin2_b = (const float*)d_in[17];

  float* Ax            = (float*)d_ws;                     // x1 fp32, BHL
  unsigned short* Zb   = (unsigned short*)(Ax + BHLq);     // z bf16, BHL
  unsigned short* Cb   = Zb + BHLq;                        // gelu(y) bf16, BHL
  float* Kbuf          = (float*)(Cb + BHLq);              // 2*H*L fp32
  float* Part          = Kbuf + 2*HLq;                     // 16 x B x 2048 fp32 partials
  float* scsh          = Part + 16*64*2048;                // B*2048 fp32
  unsigned short* wb   = (unsigned short*)(scsh + 64*2048);// 3 x 256*256 bf16 weights
  float* out           = (float*)d_out;

  k_wcvt  <<<192, 256, 0, stream>>>(out_w, lin1_w, lin2_w, wb);
  k_ada2  <<<dim3(32, 16), 256, 0, stream>>>(t, ada_w, Part);
  k_red   <<<128, 256, 0, stream>>>(Part, ada_b, scsh);
  k_adaln <<<Bq*Hq, 256, 0, stream>>>(x, scsh, Ax);
  k_chln2 <<<dim3(16, Bq), 256, 0, stream>>>(Ax, norm_w, norm_b, Zb);
  k_ssmk  <<<dim3(4, Hq), 256, 0, stream>>>(log_dt, A_re, A_im, C_re, C_im, Kbuf);
  k_conv  <<<dim3(2, Hq), 256, 0, stream>>>(Zb, Kbuf, Dp, Cb);
  k_fuse  <<<dim3(16, Bq), 512, 0, stream>>>(Cb, wb, out_b, wb + 65536, lin1_b,
                                             wb + 131072, lin2_b, Ax, out);
}

// Round 12
// 434.268 us; speedup vs baseline: 1.4279x; 1.0436x over previous
//
#include <hip/hip_runtime.h>
#include <math.h>

#define Bq 64
#define Hq 256
#define Lq 1024
#define HLq (Hq*Lq)        // 262144
#define BHLq (Bq*Hq*Lq)    // 16777216
#define HNq (Hq*64)        // 16384

typedef __attribute__((ext_vector_type(8))) short bf16x8;
typedef __attribute__((ext_vector_type(4))) float f32x4;

__device__ __forceinline__ float sigmoidf_(float x){ return 1.f/(1.f+expf(-x)); }
__device__ __forceinline__ unsigned short f2bf(float f){
  unsigned u = __float_as_uint(f);
  u += 0x7FFF + ((u>>16)&1);
  return (unsigned short)(u>>16);
}
__device__ __forceinline__ float bf2f(unsigned short h){ return __uint_as_float(((unsigned)h)<<16); }

// ---------------- K1a: ada linear partials. Grid (32 o-tiles, 16 k-chunks), 512 blocks.
__global__ __launch_bounds__(256) void k_ada2(const int* __restrict__ tptr,
        const float* __restrict__ ada_w, float* __restrict__ Part){
  __shared__ float Es[64][68];
  __shared__ float Ws[64][68];
  const int tid = threadIdx.x;
  const int o0 = blockIdx.x * 64;
  const int kc = blockIdx.y;
  const int k0 = kc * 64;
  const float ci = -logf(10000.f) / 511.f;
  #pragma unroll
  for (int it = 0; it < 4; ++it){
    int fidx = it*256 + tid;
    int row = fidx >> 4;        // b
    int c4  = fidx & 15;
    float tb = (float)tptr[row];
    float4 v;
    float* vp = &v.x;
    #pragma unroll
    for (int q = 0; q < 4; ++q){
      int k = k0 + c4*4 + q;
      float f = expf(ci * (float)(k & 511));
      float arg = tb * f;
      float s = (k < 512) ? sinf(arg) : cosf(arg);
      vp[q] = s * sigmoidf_(s);
    }
    *(float4*)&Es[row][c4*4] = v;
  }
  #pragma unroll
  for (int it = 0; it < 4; ++it){
    int fidx = it*256 + tid;
    int row = fidx >> 4;        // o
    int c4  = fidx & 15;
    *(float4*)&Ws[row][c4*4] = *(const float4*)(ada_w + (size_t)(o0+row)*1024 + k0 + c4*4);
  }
  __syncthreads();
  float acc[4][4] = {};
  #pragma unroll
  for (int ks = 0; ks < 16; ++ks){
    int k = ks*4;
    float4 ev[4], wv[4];
    #pragma unroll
    for (int i=0;i<4;++i) ev[i] = *(const float4*)&Es[(tid>>4) + 16*i][k];
    #pragma unroll
    for (int j=0;j<4;++j) wv[j] = *(const float4*)&Ws[(tid&15) + 16*j][k];
    #pragma unroll
    for (int i=0;i<4;++i)
      #pragma unroll
      for (int j=0;j<4;++j)
        acc[i][j] += ev[i].x*wv[j].x + ev[i].y*wv[j].y + ev[i].z*wv[j].z + ev[i].w*wv[j].w;
  }
  float* pbase = Part + (size_t)kc*131072 + o0;   // Part[kc][b][o]
  #pragma unroll
  for (int i=0;i<4;++i){
    int b = (tid>>4) + 16*i;
    #pragma unroll
    for (int j=0;j<4;++j){
      int o = (tid&15) + 16*j;
      pbase[(size_t)b*2048 + o] = acc[i][j];
    }
  }
}

// ---------------- K1b: reduce 16 K-partials + bias -> scsh (B x 2048)
__global__ void k_red(const float* __restrict__ Part, const float* __restrict__ ada_b,
                      float* __restrict__ scsh){
  int idx = blockIdx.x*256 + threadIdx.x;   // float4 index, 32768 total
  float4 s = ((const float4*)ada_b)[idx & 511];
  #pragma unroll
  for (int p = 0; p < 16; ++p){
    float4 u = ((const float4*)Part)[p*32768 + idx];
    s.x += u.x; s.y += u.y; s.z += u.z; s.w += u.w;
  }
  ((float4*)scsh)[idx] = s;
}

// ---------------- K1c: convert out_w / lin1_w / lin2_w (256x256 fp32) -> bf16, L2-resident
__global__ void k_wcvt(const float* __restrict__ w0, const float* __restrict__ w1,
                       const float* __restrict__ w2, unsigned short* __restrict__ wb){
  int idx = blockIdx.x*256 + threadIdx.x;   // float4 units, 49152 total
  const float* src = (idx < 16384) ? w0 : ((idx < 32768) ? w1 : w2);
  int loc = idx & 16383;
  float4 v = ((const float4*)src)[loc];
  uint2 pk;
  pk.x = (unsigned)f2bf(v.x) | ((unsigned)f2bf(v.y)<<16);
  pk.y = (unsigned)f2bf(v.z) | ((unsigned)f2bf(v.w)<<16);
  ((uint2*)wb)[idx] = pk;
}

// ---------------- K2: AdaLayerNorm over L per (b,h) row -> Ax (fp32)
__global__ void k_adaln(const float* __restrict__ x, const float* __restrict__ scsh,
                        float* __restrict__ A){
  const int bid = blockIdx.x;        // b*H + h
  const int b = bid >> 8;
  const int tid = threadIdx.x;
  const float4* row = (const float4*)(x + (size_t)bid*1024);
  float4 v = row[tid];
  float s = v.x+v.y+v.z+v.w;
  float ss = v.x*v.x+v.y*v.y+v.z*v.z+v.w*v.w;
  #pragma unroll
  for (int off=32; off; off>>=1){ s += __shfl_xor(s,off); ss += __shfl_xor(ss,off); }
  __shared__ float rs_[4], rss_[4];
  int lane = tid & 63, w = tid >> 6;
  if (!lane){ rs_[w]=s; rss_[w]=ss; }
  __syncthreads();
  s  = rs_[0]+rs_[1]+rs_[2]+rs_[3];
  ss = rss_[0]+rss_[1]+rss_[2]+rss_[3];
  float mean = s * (1.f/1024.f);
  float var  = ss*(1.f/1024.f) - mean*mean;
  float rstd = rsqrtf(var + 1e-5f);
  float4 sc = ((const float4*)(scsh + b*2048))[tid];
  float4 sh = ((const float4*)(scsh + b*2048 + 1024))[tid];
  float4 o;
  o.x = (v.x-mean)*rstd*(1.f+sc.x) + sh.x;
  o.y = (v.y-mean)*rstd*(1.f+sc.y) + sh.y;
  o.z = (v.z-mean)*rstd*(1.f+sc.z) + sh.z;
  o.w = (v.w-mean)*rstd*(1.f+sc.w) + sh.w;
  ((float4*)(A + (size_t)bid*1024))[tid] = o;
}

// ---------------- K3: channel-LN, FUSED stats + normalize.
__global__ __launch_bounds__(256) void k_chln2(const float* __restrict__ A,
        const float* __restrict__ nw, const float* __restrict__ nb,
        unsigned short* __restrict__ Zb){
  const int b  = blockIdx.y;
  const int lt = threadIdx.x & 63;
  const int hc = threadIdx.x >> 6;          // 0..3
  const int l  = blockIdx.x*64 + lt;
  const float* p = A + (size_t)b*HLq + (size_t)hc*64*1024 + l;
  float s = 0.f, ss = 0.f;
  #pragma unroll 8
  for (int h = 0; h < 64; ++h){ float v = p[(size_t)h*1024]; s += v; ss += v*v; }
  __shared__ float sp[4][64], ssp[4][64];
  __shared__ float mS[64], rS[64];
  sp[hc][lt] = s; ssp[hc][lt] = ss;
  __syncthreads();
  if (threadIdx.x < 64){
    int li = threadIdx.x;
    float st  = sp[0][li]+sp[1][li]+sp[2][li]+sp[3][li];
    float sst = ssp[0][li]+ssp[1][li]+ssp[2][li]+ssp[3][li];
    float m = st*(1.f/256.f);
    float var = sst*(1.f/256.f) - m*m;
    mS[li] = m; rS[li] = rsqrtf(var + 1e-5f);
  }
  __syncthreads();
  float m = mS[lt], r = rS[lt];
  unsigned short* zb = Zb + (size_t)b*HLq + l;
  #pragma unroll 4
  for (int h = 0; h < 64; ++h){
    int hh = hc*64 + h;
    float v = p[(size_t)h*1024];
    zb[(size_t)hh*1024] = f2bf((v-m)*r*nw[hh] + nb[hh]);
  }
}

// ---------------- K4: SSM kernels K0/K1 (2,H,L) via direct Vandermonde sum (fp32)
__global__ void k_ssmk(const float* __restrict__ log_dt, const float* __restrict__ A_re,
                       const float* __restrict__ A_im, const float* __restrict__ C_re,
                       const float* __restrict__ C_im, float* __restrict__ Kbuf){
  const int h = blockIdx.y;
  const int tid = threadIdx.x;
  __shared__ float dre[64], dim_[64], c0r[64], c0i[64], c1r[64], c1i[64];
  if (tid < 64){
    int n = tid;
    float dt = expf(log_dt[h]);
    float Ar = -expf(A_re[h*64+n]);
    float Ai = A_im[h*64+n];
    float dr = dt*Ar, di = dt*Ai;
    float er = expf(dr);
    float dAr = er*cosf(di), dAi = er*sinf(di);
    float den = Ar*Ar + Ai*Ai;
    float nr = dAr - 1.f, ni = dAi;
    float qr = (nr*Ar + ni*Ai)/den;
    float qi = (ni*Ar - nr*Ai)/den;
    float C0r = C_re[h*64+n],       C0i = C_im[h*64+n];
    float C1r = C_re[HNq + h*64+n], C1i = C_im[HNq + h*64+n];
    c0r[n] = C0r*qr - C0i*qi; c0i[n] = C0r*qi + C0i*qr;
    c1r[n] = C1r*qr - C1i*qi; c1i[n] = C1r*qi + C1i*qr;
    dre[n] = dr; dim_[n] = di;
  }
  __syncthreads();
  int l = blockIdx.x*256 + tid;
  float lf = (float)l;
  float a0=0.f, a1=0.f;
  for (int n=0;n<64;++n){
    float e  = expf(lf*dre[n]);
    float ph = lf*dim_[n];
    float wr = e*cosf(ph), wi = e*sinf(ph);
    a0 += c0r[n]*wr - c0i[n]*wi;
    a1 += c1r[n]*wr - c1i[n]*wi;
  }
  Kbuf[h*1024 + l]       = 2.f*a0;
  Kbuf[HLq + h*1024 + l] = 2.f*a1;
}

// ---------------- K5: bidirectional Toeplitz conv (v2: 512 thr / 8 waves).
// Each wave owns a 64-wide N-strip (was 128): per-wave acc 4x4 f32x4 = 64 VGPR
// (was 128) -> demand ~120 -> 4 waves/SIMD -> 2 blocks/CU = 16 waves/CU (2x).
// LDS 50.3KB x 2 = 100.6KB. Grid (2,256) = 512 blocks = exactly 2/CU.
__global__ __launch_bounds__(512,2) void k_conv(const unsigned short* __restrict__ Zb,
        const float* __restrict__ Kbuf, const float* __restrict__ Dp,
        unsigned short* __restrict__ Cb){
  __shared__ unsigned short kcopy[8][2056];   // stride 2056 el = 1028 dw = 4 mod 32 (bank spread)
  __shared__ unsigned short As[64][136];      // z tile, Kc=128, +8 pad
  const int tid = threadIdx.x;
  const int h  = blockIdx.y;
  const int l0 = blockIdx.x * 512;
  const float* K0 = Kbuf + h*1024;
  const float* K1 = Kbuf + HLq + h*1024;
  for (int idx = tid; idx < 8*2056; idx += 512){
    int s = idx / 2056;
    int i = idx - s*2056;
    int q = 2046 - i - s;
    float v = 0.f;
    if (q >= 0) v = (q >= 1023) ? K0[q-1023] : K1[1022-q];
    kcopy[s][i] = f2bf(v);
  }
  const int lane = tid & 63;
  const int w    = tid >> 6;      // 0..7
  const int ln   = lane & 15;
  const int quad = lane >> 4;
  int kofs[4];
  #pragma unroll
  for (int nt=0; nt<4; ++nt){
    int l = l0 + w*64 + nt*16 + ln;
    int d = 1023 - l;              // krev base = d + j
    int s = d & 7;
    kofs[nt] = s*2056 + (d - s) + quad*8;   // 16B-aligned element offset
  }
  const unsigned short* kbase = &kcopy[0][0];
  f32x4 acc[4][4] = {};
  for (int c = 0; c < 8; ++c){
    __syncthreads();
    #pragma unroll
    for (int pass = 0; pass < 2; ++pass){
      int b = pass*32 + (tid>>4);
      int col = (tid & 15)*8;
      *(uint4*)&As[b][col] = *(const uint4*)(Zb + ((size_t)b*256 + h)*1024 + c*128 + col);
    }
    __syncthreads();
    #pragma unroll
    for (int ks = 0; ks < 4; ++ks){
      int kk = ks*32 + quad*8;
      bf16x8 af[4];
      #pragma unroll
      for (int mt=0; mt<4; ++mt) af[mt] = *(const bf16x8*)&As[mt*16+ln][kk];
      int jb = c*128 + ks*32;
      bf16x8 bv[4];
      #pragma unroll
      for (int nt=0; nt<4; ++nt) bv[nt] = *(const bf16x8*)(kbase + kofs[nt] + jb);
      #pragma unroll
      for (int mt=0; mt<4; ++mt)
        #pragma unroll
        for (int nt=0; nt<4; ++nt)
          acc[mt][nt] = __builtin_amdgcn_mfma_f32_16x16x32_bf16(af[mt], bv[nt], acc[mt][nt], 0,0,0);
    }
  }
  float Dh = Dp[h];
  #pragma unroll
  for (int mt=0; mt<4; ++mt){
    #pragma unroll
    for (int reg=0; reg<4; ++reg){
      int b = mt*16 + quad*4 + reg;
      const unsigned short* zrow = Zb + ((size_t)b*256+h)*1024;
      unsigned short* crow = Cb + ((size_t)b*256+h)*1024;
      #pragma unroll
      for (int nt=0; nt<4; ++nt){
        int l = l0 + w*64 + nt*16 + ln;
        float y = acc[mt][nt][reg] + Dh*bf2f(zrow[l]);
        float g = 0.5f*y*(1.f + erff(y*0.70710678118f));
        crow[l] = f2bf(g);
      }
    }
  }
}

// ---------------- K6: FUSED gate + dual output GEMM (v7 — measured 93us, VGPR 64, no spill).
__global__ __launch_bounds__(512,3)
void k_fuse(const unsigned short* __restrict__ U,
        const unsigned short* __restrict__ Wob, const float* __restrict__ out_b,
        const unsigned short* __restrict__ W1b, const float* __restrict__ b1,
        const unsigned short* __restrict__ W2b, const float* __restrict__ b2,
        const float* __restrict__ Ax, float* __restrict__ out){
  __shared__ unsigned short Ts[64][264];
  const int tid = threadIdx.x;
  const int l0 = blockIdx.x * 64;
  const int b  = blockIdx.y;
  const int lane = tid & 63, w = tid >> 6, ln = lane & 15, quad = lane >> 4;
  // ---- stage: Ts[l][i] = U[b][i][l0+l]  (transpose gather, 4 i per uint2)
  {
    int l   = tid & 63;
    int grp = tid >> 6;            // 0..7
    #pragma unroll
    for (int it = 0; it < 8; ++it){
      int i4 = it*8 + grp;         // 0..63
      const unsigned short* usrc = U + ((size_t)b*256 + i4*4)*1024 + l0 + l;
      unsigned short e0 = usrc[0], e1 = usrc[1024], e2 = usrc[2048], e3 = usrc[3072];
      uint2 val; val.x = (unsigned)e0 | ((unsigned)e1<<16); val.y = (unsigned)e2 | ((unsigned)e3<<16);
      *(uint2*)&Ts[l][i4*4] = val;
    }
  }
  __syncthreads();
  // ---- GEMM1: x2 for o in [w*32, w*32+32), l-tile 64 (nt=0..3)
  f32x4 acc1[2][4] = {};
  #pragma unroll
  for (int ks = 0; ks < 8; ++ks){
    int kk = ks*32 + quad*8;
    bf16x8 af[2], bv[4];
    #pragma unroll
    for (int mt=0;mt<2;++mt) af[mt] = *(const bf16x8*)(Wob + (size_t)(w*32+mt*16+ln)*256 + kk);
    #pragma unroll
    for (int nt=0;nt<4;++nt) bv[nt] = *(const bf16x8*)&Ts[nt*16+ln][kk];
    #pragma unroll
    for (int mt=0;mt<2;++mt)
      #pragma unroll
      for (int nt=0;nt<4;++nt)
        acc1[mt][nt] = __builtin_amdgcn_mfma_f32_16x16x32_bf16(af[mt], bv[nt], acc1[mt][nt],0,0,0);
  }
  // ---- gate: g = tanh(v)*sigmoid(v) = (1-t)/(1+t^2), t = e^-v (clamped)
  #pragma unroll
  for (int mt=0;mt<2;++mt){
    #pragma unroll
    for (int reg=0;reg<4;++reg){
      int o = w*32 + mt*16 + quad*4 + reg;
      float bo = out_b[o];
      const float* arow = Ax + ((size_t)b*256 + o)*1024 + l0;
      #pragma unroll
      for (int nt=0;nt<4;++nt){
        int l = nt*16 + ln;
        float v = acc1[mt][nt][reg] + bo + arow[l];
        float t = expf(-fmaxf(v, -15.f));
        acc1[mt][nt][reg] = (1.f - t)/(1.f + t*t);
      }
    }
  }
  __syncthreads();            // all waves done reading u from Ts
  // ---- write g into the same tile; column dim is now o
  #pragma unroll
  for (int mt=0;mt<2;++mt){
    int ob = w*32 + mt*16 + quad*4;
    #pragma unroll
    for (int nt=0;nt<4;++nt){
      int l = nt*16 + ln;
      uint2 pk;
      pk.x = (unsigned)f2bf(acc1[mt][nt][0]) | ((unsigned)f2bf(acc1[mt][nt][1])<<16);
      pk.y = (unsigned)f2bf(acc1[mt][nt][2]) | ((unsigned)f2bf(acc1[mt][nt][3])<<16);
      *(uint2*)&Ts[l][ob] = pk;
    }
  }
  __syncthreads();
  // ---- GEMM2 (dual), two o-halves: live accs 32 VGPR
  #pragma unroll
  for (int half = 0; half < 2; ++half){
    f32x4 accA[4] = {}, accB[4] = {};
    #pragma unroll
    for (int ks = 0; ks < 8; ++ks){
      int kk = ks*32 + quad*8;
      bf16x8 bv[4];
      #pragma unroll
      for (int nt=0;nt<4;++nt) bv[nt] = *(const bf16x8*)&Ts[nt*16+ln][kk];
      int orow = w*32 + half*16 + ln;
      bf16x8 a1 = *(const bf16x8*)(W1b + (size_t)orow*256 + kk);
      #pragma unroll
      for (int nt=0;nt<4;++nt)
        accA[nt] = __builtin_amdgcn_mfma_f32_16x16x32_bf16(a1, bv[nt], accA[nt],0,0,0);
      bf16x8 a2 = *(const bf16x8*)(W2b + (size_t)orow*256 + kk);
      #pragma unroll
      for (int nt=0;nt<4;++nt)
        accB[nt] = __builtin_amdgcn_mfma_f32_16x16x32_bf16(a2, bv[nt], accB[nt],0,0,0);
    }
    // epilogue for this half (Ax re-read; L2-hot)
    #pragma unroll
    for (int reg=0;reg<4;++reg){
      int o = w*32 + half*16 + quad*4 + reg;
      float bo1 = b1[o], bo2 = b2[o];
      const float* arow = Ax + ((size_t)b*256 + o)*1024 + l0;
      float* o1row = out + ((size_t)b*256 + o)*1024 + l0;
      float* o2row = o1row + BHLq;
      #pragma unroll
      for (int nt=0;nt<4;++nt){
        int l = nt*16 + ln;
        o1row[l] = accA[nt][reg] + bo1 + arow[l];
        o2row[l] = accB[nt][reg] + bo2;
      }
    }
  }
}

extern "C" void kernel_launch(void* const* d_in, const int* in_sizes, int n_in,
                              void* d_out, int out_size, void* d_ws, size_t ws_size,
                              hipStream_t stream){
  const float* x      = (const float*)d_in[0];
  const int*   t      = (const int*)  d_in[1];
  const float* ada_w  = (const float*)d_in[2];
  const float* ada_b  = (const float*)d_in[3];
  const float* norm_w = (const float*)d_in[4];
  const float* norm_b = (const float*)d_in[5];
  const float* log_dt = (const float*)d_in[6];
  const float* A_re   = (const float*)d_in[7];
  const float* A_im   = (const float*)d_in[8];
  const float* C_re   = (const float*)d_in[9];
  const float* C_im   = (const float*)d_in[10];
  const float* Dp     = (const float*)d_in[11];
  const float* out_w  = (const float*)d_in[12];
  const float* out_b  = (const float*)d_in[13];
  const float* lin1_w = (const float*)d_in[14];
  const float* lin1_b = (const float*)d_in[15];
  const float* lin2_w = (const float*)d_in[16];
  const float* lin2_b = (const float*)d_in[17];

  float* Ax            = (float*)d_ws;                     // x1 fp32, BHL
  unsigned short* Zb   = (unsigned short*)(Ax + BHLq);     // z bf16, BHL
  unsigned short* Cb   = Zb + BHLq;                        // gelu(y) bf16, BHL
  float* Kbuf          = (float*)(Cb + BHLq);              // 2*H*L fp32
  float* Part          = Kbuf + 2*HLq;                     // 16 x B x 2048 fp32 partials
  float* scsh          = Part + 16*64*2048;                // B*2048 fp32
  unsigned short* wb   = (unsigned short*)(scsh + 64*2048);// 3 x 256*256 bf16 weights
  float* out           = (float*)d_out;

  k_wcvt  <<<192, 256, 0, stream>>>(out_w, lin1_w, lin2_w, wb);
  k_ada2  <<<dim3(32, 16), 256, 0, stream>>>(t, ada_w, Part);
  k_red   <<<128, 256, 0, stream>>>(Part, ada_b, scsh);
  k_adaln <<<Bq*Hq, 256, 0, stream>>>(x, scsh, Ax);
  k_chln2 <<<dim3(16, Bq), 256, 0, stream>>>(Ax, norm_w, norm_b, Zb);
  k_ssmk  <<<dim3(4, Hq), 256, 0, stream>>>(log_dt, A_re, A_im, C_re, C_im, Kbuf);
  k_conv  <<<dim3(2, Hq), 512, 0, stream>>>(Zb, Kbuf, Dp, Cb);
  k_fuse  <<<dim3(16, Bq), 512, 0, stream>>>(Cb, wb, out_b, wb + 65536, lin1_b,
                                             wb + 131072, lin2_b, Ax, out);
}

// Round 13
// 429.044 us; speedup vs baseline: 1.4453x; 1.0122x over previous
//
#include <hip/hip_runtime.h>
#include <math.h>

#define Bq 64
#define Hq 256
#define Lq 1024
#define HLq (Hq*Lq)        // 262144
#define BHLq (Bq*Hq*Lq)    // 16777216
#define HNq (Hq*64)        // 16384

typedef __attribute__((ext_vector_type(8))) short bf16x8;
typedef __attribute__((ext_vector_type(4))) float f32x4;

__device__ __forceinline__ float sigmoidf_(float x){ return 1.f/(1.f+expf(-x)); }
__device__ __forceinline__ unsigned short f2bf(float f){
  unsigned u = __float_as_uint(f);
  u += 0x7FFF + ((u>>16)&1);
  return (unsigned short)(u>>16);
}
__device__ __forceinline__ float bf2f(unsigned short h){ return __uint_as_float(((unsigned)h)<<16); }

// ---------------- K1a: ada linear partials. Grid (32 o-tiles, 16 k-chunks), 512 blocks.
__global__ __launch_bounds__(256) void k_ada2(const int* __restrict__ tptr,
        const float* __restrict__ ada_w, float* __restrict__ Part){
  __shared__ float Es[64][68];
  __shared__ float Ws[64][68];
  const int tid = threadIdx.x;
  const int o0 = blockIdx.x * 64;
  const int kc = blockIdx.y;
  const int k0 = kc * 64;
  const float ci = -logf(10000.f) / 511.f;
  #pragma unroll
  for (int it = 0; it < 4; ++it){
    int fidx = it*256 + tid;
    int row = fidx >> 4;        // b
    int c4  = fidx & 15;
    float tb = (float)tptr[row];
    float4 v;
    float* vp = &v.x;
    #pragma unroll
    for (int q = 0; q < 4; ++q){
      int k = k0 + c4*4 + q;
      float f = expf(ci * (float)(k & 511));
      float arg = tb * f;
      float s = (k < 512) ? sinf(arg) : cosf(arg);
      vp[q] = s * sigmoidf_(s);
    }
    *(float4*)&Es[row][c4*4] = v;
  }
  #pragma unroll
  for (int it = 0; it < 4; ++it){
    int fidx = it*256 + tid;
    int row = fidx >> 4;        // o
    int c4  = fidx & 15;
    *(float4*)&Ws[row][c4*4] = *(const float4*)(ada_w + (size_t)(o0+row)*1024 + k0 + c4*4);
  }
  __syncthreads();
  float acc[4][4] = {};
  #pragma unroll
  for (int ks = 0; ks < 16; ++ks){
    int k = ks*4;
    float4 ev[4], wv[4];
    #pragma unroll
    for (int i=0;i<4;++i) ev[i] = *(const float4*)&Es[(tid>>4) + 16*i][k];
    #pragma unroll
    for (int j=0;j<4;++j) wv[j] = *(const float4*)&Ws[(tid&15) + 16*j][k];
    #pragma unroll
    for (int i=0;i<4;++i)
      #pragma unroll
      for (int j=0;j<4;++j)
        acc[i][j] += ev[i].x*wv[j].x + ev[i].y*wv[j].y + ev[i].z*wv[j].z + ev[i].w*wv[j].w;
  }
  float* pbase = Part + (size_t)kc*131072 + o0;   // Part[kc][b][o]
  #pragma unroll
  for (int i=0;i<4;++i){
    int b = (tid>>4) + 16*i;
    #pragma unroll
    for (int j=0;j<4;++j){
      int o = (tid&15) + 16*j;
      pbase[(size_t)b*2048 + o] = acc[i][j];
    }
  }
}

// ---------------- K1b: reduce 16 K-partials + bias -> scsh (B x 2048)
__global__ void k_red(const float* __restrict__ Part, const float* __restrict__ ada_b,
                      float* __restrict__ scsh){
  int idx = blockIdx.x*256 + threadIdx.x;   // float4 index, 32768 total
  float4 s = ((const float4*)ada_b)[idx & 511];
  #pragma unroll
  for (int p = 0; p < 16; ++p){
    float4 u = ((const float4*)Part)[p*32768 + idx];
    s.x += u.x; s.y += u.y; s.z += u.z; s.w += u.w;
  }
  ((float4*)scsh)[idx] = s;
}

// ---------------- K1c: convert out_w / lin1_w / lin2_w (256x256 fp32) -> bf16, L2-resident
__global__ void k_wcvt(const float* __restrict__ w0, const float* __restrict__ w1,
                       const float* __restrict__ w2, unsigned short* __restrict__ wb){
  int idx = blockIdx.x*256 + threadIdx.x;   // float4 units, 49152 total
  const float* src = (idx < 16384) ? w0 : ((idx < 32768) ? w1 : w2);
  int loc = idx & 16383;
  float4 v = ((const float4*)src)[loc];
  uint2 pk;
  pk.x = (unsigned)f2bf(v.x) | ((unsigned)f2bf(v.y)<<16);
  pk.y = (unsigned)f2bf(v.z) | ((unsigned)f2bf(v.w)<<16);
  ((uint2*)wb)[idx] = pk;
}

// ---------------- K2: AdaLayerNorm over L per (b,h) row -> Ax (fp32)
__global__ void k_adaln(const float* __restrict__ x, const float* __restrict__ scsh,
                        float* __restrict__ A){
  const int bid = blockIdx.x;        // b*H + h
  const int b = bid >> 8;
  const int tid = threadIdx.x;
  const float4* row = (const float4*)(x + (size_t)bid*1024);
  float4 v = row[tid];
  float s = v.x+v.y+v.z+v.w;
  float ss = v.x*v.x+v.y*v.y+v.z*v.z+v.w*v.w;
  #pragma unroll
  for (int off=32; off; off>>=1){ s += __shfl_xor(s,off); ss += __shfl_xor(ss,off); }
  __shared__ float rs_[4], rss_[4];
  int lane = tid & 63, w = tid >> 6;
  if (!lane){ rs_[w]=s; rss_[w]=ss; }
  __syncthreads();
  s  = rs_[0]+rs_[1]+rs_[2]+rs_[3];
  ss = rss_[0]+rss_[1]+rss_[2]+rss_[3];
  float mean = s * (1.f/1024.f);
  float var  = ss*(1.f/1024.f) - mean*mean;
  float rstd = rsqrtf(var + 1e-5f);
  float4 sc = ((const float4*)(scsh + b*2048))[tid];
  float4 sh = ((const float4*)(scsh + b*2048 + 1024))[tid];
  float4 o;
  o.x = (v.x-mean)*rstd*(1.f+sc.x) + sh.x;
  o.y = (v.y-mean)*rstd*(1.f+sc.y) + sh.y;
  o.z = (v.z-mean)*rstd*(1.f+sc.z) + sh.z;
  o.w = (v.w-mean)*rstd*(1.f+sc.w) + sh.w;
  ((float4*)(A + (size_t)bid*1024))[tid] = o;
}

// ---------------- K3: channel-LN, FUSED stats + normalize.
__global__ __launch_bounds__(256) void k_chln2(const float* __restrict__ A,
        const float* __restrict__ nw, const float* __restrict__ nb,
        unsigned short* __restrict__ Zb){
  const int b  = blockIdx.y;
  const int lt = threadIdx.x & 63;
  const int hc = threadIdx.x >> 6;          // 0..3
  const int l  = blockIdx.x*64 + lt;
  const float* p = A + (size_t)b*HLq + (size_t)hc*64*1024 + l;
  float s = 0.f, ss = 0.f;
  #pragma unroll 8
  for (int h = 0; h < 64; ++h){ float v = p[(size_t)h*1024]; s += v; ss += v*v; }
  __shared__ float sp[4][64], ssp[4][64];
  __shared__ float mS[64], rS[64];
  sp[hc][lt] = s; ssp[hc][lt] = ss;
  __syncthreads();
  if (threadIdx.x < 64){
    int li = threadIdx.x;
    float st  = sp[0][li]+sp[1][li]+sp[2][li]+sp[3][li];
    float sst = ssp[0][li]+ssp[1][li]+ssp[2][li]+ssp[3][li];
    float m = st*(1.f/256.f);
    float var = sst*(1.f/256.f) - m*m;
    mS[li] = m; rS[li] = rsqrtf(var + 1e-5f);
  }
  __syncthreads();
  float m = mS[lt], r = rS[lt];
  unsigned short* zb = Zb + (size_t)b*HLq + l;
  #pragma unroll 4
  for (int h = 0; h < 64; ++h){
    int hh = hc*64 + h;
    float v = p[(size_t)h*1024];
    zb[(size_t)hh*1024] = f2bf((v-m)*r*nw[hh] + nb[hh]);
  }
}

// ---------------- K4: SSM kernels K0/K1 (2,H,L) via direct Vandermonde sum (fp32)
__global__ void k_ssmk(const float* __restrict__ log_dt, const float* __restrict__ A_re,
                       const float* __restrict__ A_im, const float* __restrict__ C_re,
                       const float* __restrict__ C_im, float* __restrict__ Kbuf){
  const int h = blockIdx.y;
  const int tid = threadIdx.x;
  __shared__ float dre[64], dim_[64], c0r[64], c0i[64], c1r[64], c1i[64];
  if (tid < 64){
    int n = tid;
    float dt = expf(log_dt[h]);
    float Ar = -expf(A_re[h*64+n]);
    float Ai = A_im[h*64+n];
    float dr = dt*Ar, di = dt*Ai;
    float er = expf(dr);
    float dAr = er*cosf(di), dAi = er*sinf(di);
    float den = Ar*Ar + Ai*Ai;
    float nr = dAr - 1.f, ni = dAi;
    float qr = (nr*Ar + ni*Ai)/den;
    float qi = (ni*Ar - nr*Ai)/den;
    float C0r = C_re[h*64+n],       C0i = C_im[h*64+n];
    float C1r = C_re[HNq + h*64+n], C1i = C_im[HNq + h*64+n];
    c0r[n] = C0r*qr - C0i*qi; c0i[n] = C0r*qi + C0i*qr;
    c1r[n] = C1r*qr - C1i*qi; c1i[n] = C1r*qi + C1i*qr;
    dre[n] = dr; dim_[n] = di;
  }
  __syncthreads();
  int l = blockIdx.x*256 + tid;
  float lf = (float)l;
  float a0=0.f, a1=0.f;
  for (int n=0;n<64;++n){
    float e  = expf(lf*dre[n]);
    float ph = lf*dim_[n];
    float wr = e*cosf(ph), wi = e*sinf(ph);
    a0 += c0r[n]*wr - c0i[n]*wi;
    a1 += c1r[n]*wr - c1i[n]*wi;
  }
  Kbuf[h*1024 + l]       = 2.f*a0;
  Kbuf[HLq + h*1024 + l] = 2.f*a1;
}

// ---------------- K5: bidirectional Toeplitz conv (v2: 512 thr / 8 waves).
__global__ __launch_bounds__(512,2) void k_conv(const unsigned short* __restrict__ Zb,
        const float* __restrict__ Kbuf, const float* __restrict__ Dp,
        unsigned short* __restrict__ Cb){
  __shared__ unsigned short kcopy[8][2056];   // stride 2056 el = 1028 dw = 4 mod 32 (bank spread)
  __shared__ unsigned short As[64][136];      // z tile, Kc=128, +8 pad
  const int tid = threadIdx.x;
  const int h  = blockIdx.y;
  const int l0 = blockIdx.x * 512;
  const float* K0 = Kbuf + h*1024;
  const float* K1 = Kbuf + HLq + h*1024;
  for (int idx = tid; idx < 8*2056; idx += 512){
    int s = idx / 2056;
    int i = idx - s*2056;
    int q = 2046 - i - s;
    float v = 0.f;
    if (q >= 0) v = (q >= 1023) ? K0[q-1023] : K1[1022-q];
    kcopy[s][i] = f2bf(v);
  }
  const int lane = tid & 63;
  const int w    = tid >> 6;      // 0..7
  const int ln   = lane & 15;
  const int quad = lane >> 4;
  int kofs[4];
  #pragma unroll
  for (int nt=0; nt<4; ++nt){
    int l = l0 + w*64 + nt*16 + ln;
    int d = 1023 - l;              // krev base = d + j
    int s = d & 7;
    kofs[nt] = s*2056 + (d - s) + quad*8;   // 16B-aligned element offset
  }
  const unsigned short* kbase = &kcopy[0][0];
  f32x4 acc[4][4] = {};
  for (int c = 0; c < 8; ++c){
    __syncthreads();
    #pragma unroll
    for (int pass = 0; pass < 2; ++pass){
      int b = pass*32 + (tid>>4);
      int col = (tid & 15)*8;
      *(uint4*)&As[b][col] = *(const uint4*)(Zb + ((size_t)b*256 + h)*1024 + c*128 + col);
    }
    __syncthreads();
    #pragma unroll
    for (int ks = 0; ks < 4; ++ks){
      int kk = ks*32 + quad*8;
      bf16x8 af[4];
      #pragma unroll
      for (int mt=0; mt<4; ++mt) af[mt] = *(const bf16x8*)&As[mt*16+ln][kk];
      int jb = c*128 + ks*32;
      bf16x8 bv[4];
      #pragma unroll
      for (int nt=0; nt<4; ++nt) bv[nt] = *(const bf16x8*)(kbase + kofs[nt] + jb);
      #pragma unroll
      for (int mt=0; mt<4; ++mt)
        #pragma unroll
        for (int nt=0; nt<4; ++nt)
          acc[mt][nt] = __builtin_amdgcn_mfma_f32_16x16x32_bf16(af[mt], bv[nt], acc[mt][nt], 0,0,0);
    }
  }
  float Dh = Dp[h];
  #pragma unroll
  for (int mt=0; mt<4; ++mt){
    #pragma unroll
    for (int reg=0; reg<4; ++reg){
      int b = mt*16 + quad*4 + reg;
      const unsigned short* zrow = Zb + ((size_t)b*256+h)*1024;
      unsigned short* crow = Cb + ((size_t)b*256+h)*1024;
      #pragma unroll
      for (int nt=0; nt<4; ++nt){
        int l = l0 + w*64 + nt*16 + ln;
        float y = acc[mt][nt][reg] + Dh*bf2f(zrow[l]);
        float g = 0.5f*y*(1.f + erff(y*0.70710678118f));
        crow[l] = f2bf(g);
      }
    }
  }
}

// ---------------- K6: FUSED gate + dual output GEMM (v8).
// v7 + GEMM1 split into two o-halves with immediate gate+pack (gpk held in regs):
// peak live accs 32->16+8, total demand ~55-60 incl MFMA accumulators, so true
// (unified VGPR+AGPR) usage fits 64 -> 8 waves/SIMD -> 4 blocks/CU (LDS 135KB ok)
// -> grid 1024 == capacity exactly, zero tail. launch_bounds(512,4): cap 128,
// demand ~60, 2x margin (r8's spill was demand 75 > cap 64 — not repeatable here).
// Gate for post-mortem: WRITE ~131MB (no spill), Occupancy >= 60%.
__global__ __launch_bounds__(512,4)
void k_fuse(const unsigned short* __restrict__ U,
        const unsigned short* __restrict__ Wob, const float* __restrict__ out_b,
        const unsigned short* __restrict__ W1b, const float* __restrict__ b1,
        const unsigned short* __restrict__ W2b, const float* __restrict__ b2,
        const float* __restrict__ Ax, float* __restrict__ out){
  __shared__ unsigned short Ts[64][264];
  const int tid = threadIdx.x;
  const int l0 = blockIdx.x * 64;
  const int b  = blockIdx.y;
  const int lane = tid & 63, w = tid >> 6, ln = lane & 15, quad = lane >> 4;
  // ---- stage: Ts[l][i] = U[b][i][l0+l]  (transpose gather, 4 i per uint2)
  {
    int l   = tid & 63;
    int grp = tid >> 6;            // 0..7
    #pragma unroll
    for (int it = 0; it < 8; ++it){
      int i4 = it*8 + grp;         // 0..63
      const unsigned short* usrc = U + ((size_t)b*256 + i4*4)*1024 + l0 + l;
      unsigned short e0 = usrc[0], e1 = usrc[1024], e2 = usrc[2048], e3 = usrc[3072];
      uint2 val; val.x = (unsigned)e0 | ((unsigned)e1<<16); val.y = (unsigned)e2 | ((unsigned)e3<<16);
      *(uint2*)&Ts[l][i4*4] = val;
    }
  }
  __syncthreads();
  // ---- GEMM1 + gate, two o-halves (16 o-rows each); g packed in regs
  uint2 gpk[2][4];   // [half][nt]
  #pragma unroll
  for (int half = 0; half < 2; ++half){
    f32x4 acc1[4] = {};
    #pragma unroll
    for (int ks = 0; ks < 8; ++ks){
      int kk = ks*32 + quad*8;
      bf16x8 af = *(const bf16x8*)(Wob + (size_t)(w*32+half*16+ln)*256 + kk);
      bf16x8 bv[4];
      #pragma unroll
      for (int nt=0;nt<4;++nt) bv[nt] = *(const bf16x8*)&Ts[nt*16+ln][kk];
      #pragma unroll
      for (int nt=0;nt<4;++nt)
        acc1[nt] = __builtin_amdgcn_mfma_f32_16x16x32_bf16(af, bv[nt], acc1[nt],0,0,0);
    }
    // gate: g = tanh(v)*sigmoid(v) = (1-t)/(1+t^2), t = e^-v (clamped)
    #pragma unroll
    for (int reg=0;reg<4;++reg){
      int o = w*32 + half*16 + quad*4 + reg;
      float bo = out_b[o];
      const float* arow = Ax + ((size_t)b*256 + o)*1024 + l0;
      #pragma unroll
      for (int nt=0;nt<4;++nt){
        int l = nt*16 + ln;
        float v = acc1[nt][reg] + bo + arow[l];
        float t = expf(-fmaxf(v, -15.f));
        acc1[nt][reg] = (1.f - t)/(1.f + t*t);
      }
    }
    #pragma unroll
    for (int nt=0;nt<4;++nt){
      uint2 pk;
      pk.x = (unsigned)f2bf(acc1[nt][0]) | ((unsigned)f2bf(acc1[nt][1])<<16);
      pk.y = (unsigned)f2bf(acc1[nt][2]) | ((unsigned)f2bf(acc1[nt][3])<<16);
      gpk[half][nt] = pk;
    }
  }
  __syncthreads();            // all waves done reading u from Ts
  // ---- write g into the same tile; column dim is now o
  #pragma unroll
  for (int half=0;half<2;++half){
    int ob = w*32 + half*16 + quad*4;
    #pragma unroll
    for (int nt=0;nt<4;++nt){
      int l = nt*16 + ln;
      *(uint2*)&Ts[l][ob] = gpk[half][nt];
    }
  }
  __syncthreads();
  // ---- GEMM2 (dual), two o-halves: live accs 32 VGPR
  #pragma unroll
  for (int half = 0; half < 2; ++half){
    f32x4 accA[4] = {}, accB[4] = {};
    #pragma unroll
    for (int ks = 0; ks < 8; ++ks){
      int kk = ks*32 + quad*8;
      bf16x8 bv[4];
      #pragma unroll
      for (int nt=0;nt<4;++nt) bv[nt] = *(const bf16x8*)&Ts[nt*16+ln][kk];
      int orow = w*32 + half*16 + ln;
      bf16x8 a1 = *(const bf16x8*)(W1b + (size_t)orow*256 + kk);
      #pragma unroll
      for (int nt=0;nt<4;++nt)
        accA[nt] = __builtin_amdgcn_mfma_f32_16x16x32_bf16(a1, bv[nt], accA[nt],0,0,0);
      bf16x8 a2 = *(const bf16x8*)(W2b + (size_t)orow*256 + kk);
      #pragma unroll
      for (int nt=0;nt<4;++nt)
        accB[nt] = __builtin_amdgcn_mfma_f32_16x16x32_bf16(a2, bv[nt], accB[nt],0,0,0);
    }
    // epilogue for this half (Ax re-read; L2-hot)
    #pragma unroll
    for (int reg=0;reg<4;++reg){
      int o = w*32 + half*16 + quad*4 + reg;
      float bo1 = b1[o], bo2 = b2[o];
      const float* arow = Ax + ((size_t)b*256 + o)*1024 + l0;
      float* o1row = out + ((size_t)b*256 + o)*1024 + l0;
      float* o2row = o1row + BHLq;
      #pragma unroll
      for (int nt=0;nt<4;++nt){
        int l = nt*16 + ln;
        o1row[l] = accA[nt][reg] + bo1 + arow[l];
        o2row[l] = accB[nt][reg] + bo2;
      }
    }
  }
}

extern "C" void kernel_launch(void* const* d_in, const int* in_sizes, int n_in,
                              void* d_out, int out_size, void* d_ws, size_t ws_size,
                              hipStream_t stream){
  const float* x      = (const float*)d_in[0];
  const int*   t      = (const int*)  d_in[1];
  const float* ada_w  = (const float*)d_in[2];
  const float* ada_b  = (const float*)d_in[3];
  const float* norm_w = (const float*)d_in[4];
  const float* norm_b = (const float*)d_in[5];
  const float* log_dt = (const float*)d_in[6];
  const float* A_re   = (const float*)d_in[7];
  const float* A_im   = (const float*)d_in[8];
  const float* C_re   = (const float*)d_in[9];
  const float* C_im   = (const float*)d_in[10];
  const float* Dp     = (const float*)d_in[11];
  const float* out_w  = (const float*)d_in[12];
  const float* out_b  = (const float*)d_in[13];
  const float* lin1_w = (const float*)d_in[14];
  const float* lin1_b = (const float*)d_in[15];
  const float* lin2_w = (const float*)d_in[16];
  const float* lin2_b = (const float*)d_in[17];

  float* Ax            = (float*)d_ws;                     // x1 fp32, BHL
  unsigned short* Zb   = (unsigned short*)(Ax + BHLq);     // z bf16, BHL
  unsigned short* Cb   = Zb + BHLq;                        // gelu(y) bf16, BHL
  float* Kbuf          = (float*)(Cb + BHLq);              // 2*H*L fp32
  float* Part          = Kbuf + 2*HLq;                     // 16 x B x 2048 fp32 partials
  float* scsh          = Part + 16*64*2048;                // B*2048 fp32
  unsigned short* wb   = (unsigned short*)(scsh + 64*2048);// 3 x 256*256 bf16 weights
  float* out           = (float*)d_out;

  k_wcvt  <<<192, 256, 0, stream>>>(out_w, lin1_w, lin2_w, wb);
  k_ada2  <<<dim3(32, 16), 256, 0, stream>>>(t, ada_w, Part);
  k_red   <<<128, 256, 0, stream>>>(Part, ada_b, scsh);
  k_adaln <<<Bq*Hq, 256, 0, stream>>>(x, scsh, Ax);
  k_chln2 <<<dim3(16, Bq), 256, 0, stream>>>(Ax, norm_w, norm_b, Zb);
  k_ssmk  <<<dim3(4, Hq), 256, 0, stream>>>(log_dt, A_re, A_im, C_re, C_im, Kbuf);
  k_conv  <<<dim3(2, Hq), 512, 0, stream>>>(Zb, Kbuf, Dp, Cb);
  k_fuse  <<<dim3(16, Bq), 512, 0, stream>>>(Cb, wb, out_b, wb + 65536, lin1_b,
                                             wb + 131072, lin2_b, Ax, out);
}